// Round 7
// baseline (665.564 us; speedup 1.0000x reference)
//
#include <hip/hip_runtime.h>
#include <hip/hip_bf16.h>
#include <math.h>

typedef __attribute__((ext_vector_type(8))) short short8;
typedef __attribute__((ext_vector_type(4))) float f32x4;
typedef __attribute__((ext_vector_type(4))) unsigned short us4;
typedef unsigned short u16;
typedef unsigned long long u64;

#define TM 49
#define NV 10000
#define NWG 64

union U64c { us4 v; u64 u; };

__device__ __forceinline__ u16 f2bf(float f) {
    union { float f; unsigned u; } v; v.f = f;
    unsigned r = v.u + 0x7fffu + ((v.u >> 16) & 1u);
    return (u16)(r >> 16);
}
__device__ __forceinline__ float bf2f(u16 b) {
    union { unsigned u; float f; } v; v.u = ((unsigned)b) << 16;
    return v.f;
}
__device__ __forceinline__ float sigm(float x) { return 1.0f / (1.0f + expf(-x)); }

// ---------------- sort + metadata + compaction tables + small outputs ----------------
__global__ __launch_bounds__(128) void k_sort(
    const int* __restrict__ caplens, const int* __restrict__ captions,
    const float* __restrict__ bih, const float* __restrict__ bhh,
    int* __restrict__ sidx, int* __restrict__ decl, int* __restrict__ capsS,
    float* __restrict__ bsum, float* __restrict__ out_tail,
    unsigned* __restrict__ slots, int* __restrict__ offs, int* __restrict__ rowmap)
{
    __shared__ int s_cl[128];
    __shared__ int s_si[128];
    __shared__ int s_dl[128];
    __shared__ int s_n[49];
    __shared__ int s_off[50];
    int tid = threadIdx.x;
    for (int k = tid; k < 256; k += 128)   // reset per-group barrier slots
        __hip_atomic_store(&slots[k], 0u, __ATOMIC_RELAXED, __HIP_MEMORY_SCOPE_AGENT);
    int my = caplens[tid];
    s_cl[tid] = my;
    __syncthreads();
    int r = 0;
    for (int j = 0; j < 128; j++) {
        int cj = s_cl[j];
        if (cj > my || (cj == my && j < tid)) r++;
    }
    s_si[r] = tid;   // stable descending argsort
    __syncthreads();
    int src = s_si[tid];
    sidx[tid] = src;
    int dl = s_cl[src] - 1;
    decl[tid] = dl;
    s_dl[tid] = dl;
    out_tail[6400 + tid] = (float)dl;
    out_tail[6528 + tid] = (float)src;
    for (int t = 0; t < 50; t++) {
        int tok = captions[src * 50 + t];
        capsS[tid * 50 + t] = tok;
        out_tail[tid * 50 + t] = (float)tok;
    }
    for (int k = tid; k < 2048; k += 128) bsum[k] = bih[k] + bhh[k];
    __syncthreads();
    // n_t = #valid rows at step t (rows sorted desc -> valid rows are prefix 0..n_t)
    if (tid < 49) {
        int c = 0;
        for (int b = 0; b < 128; b++) c += (s_dl[b] > tid);
        s_n[tid] = c;
    }
    __syncthreads();
    if (tid == 0) {
        int a = 0;
        for (int t = 0; t < 49; t++) { s_off[t] = a; a += s_n[t]; }
        s_off[49] = a;   // total compacted rows
    }
    __syncthreads();
    if (tid < 50) offs[tid] = s_off[tid];
    for (int t = 0; t < dl; t++) rowmap[s_off[t] + tid] = t * 128 + tid;
}

// ---------------- zero-fill masked prediction rows ----------------
__global__ __launch_bounds__(256) void k_zero(
    const int* __restrict__ decl, float* __restrict__ out)
{
    int r = blockIdx.x;           // 0..6271
    int b = r / 49, t = r - b * 49;
    if (t < decl[b]) return;
    float* dst = out + (size_t)b * 490000 + (size_t)t * 10000;
    f32x4 z = {};
    for (int i = threadIdx.x; i < 2500; i += 256) *(f32x4*)&dst[i * 4] = z;
}

// ---------------- weight fp32 -> bf16 conversion ----------------
__global__ __launch_bounds__(256) void k_cvt(
    const float* __restrict__ Wih, const float* __restrict__ Whh,
    const float* __restrict__ fcW, const float* __restrict__ ihW,
    const float* __restrict__ icW,
    u16* __restrict__ WihB, u16* __restrict__ WhhB,
    u16* __restrict__ fcWB, u16* __restrict__ WhcB)
{
    int idx = blockIdx.x * 256 + threadIdx.x;  // float4 index, exact grid
    const float* src; u16* dst; int o;
    if (idx < 262144)        { src = Wih; dst = WihB; o = idx; }
    else if (idx < 524288)   { src = Whh; dst = WhhB; o = idx - 262144; }
    else if (idx < 1804288)  { src = fcW; dst = fcWB; o = idx - 524288; }
    else if (idx < 2066432)  { src = ihW; dst = WhcB; o = idx - 1804288; }
    else                     { src = icW; dst = WhcB + 1048576; o = idx - 2066432; }
    f32x4 v = *(const f32x4*)&src[(size_t)o * 4];
    us4 b = { f2bf(v.x), f2bf(v.y), f2bf(v.z), f2bf(v.w) };
    *(us4*)&dst[(size_t)o * 4] = b;
}

// ---------------- gathers: sorted enc -> bf16, embedding -> bf16 ----------------
__global__ __launch_bounds__(256) void k_gather(
    const float* __restrict__ enc, const float* __restrict__ embW,
    const int* __restrict__ sidx, const int* __restrict__ capsS,
    u16* __restrict__ encB, u16* __restrict__ Xemb)
{
    int idx = blockIdx.x * 256 + threadIdx.x;
    if (idx < 65536) {
        int b = idx >> 9, k4 = idx & 511;
        f32x4 v = *(const f32x4*)&enc[(size_t)sidx[b] * 2048 + k4 * 4];
        us4 o = { f2bf(v.x), f2bf(v.y), f2bf(v.z), f2bf(v.w) };
        *(us4*)&encB[(size_t)b * 2048 + k4 * 4] = o;
    } else {
        int j = idx - 65536;              // < 802816
        int row = j >> 7, k4 = j & 127;   // row = t*128 + b
        int t = row >> 7, b = row & 127;
        int tok = capsS[b * 50 + t];
        f32x4 v = *(const f32x4*)&embW[(size_t)tok * 512 + k4 * 4];
        us4 o = { f2bf(v.x), f2bf(v.y), f2bf(v.z), f2bf(v.w) };
        *(us4*)&Xemb[(size_t)row * 512 + k4 * 4] = o;
    }
}

// ---------------- generic 128x128 bf16 MFMA GEMM, C = A * B^T ----------------
// 1D grid with grouped-supertile ordering for XCD/L2 locality.
// MODE 0: X-precompute. MODE 1: h0/c0. MODE 2: fc on COMPACTED rows (rowmap scatter).
template<int MODE>
__global__ __launch_bounds__(256) void gemm128(
    const u16* __restrict__ A, int lda,
    const u16* __restrict__ Bm, int ldb, int Nreal, int K,
    int GM, int GN,
    const float* __restrict__ bias, const float* __restrict__ bias2,
    const int* __restrict__ nrowsPtr, const int* __restrict__ rowmap,
    float* __restrict__ outF, u16* __restrict__ outH, float* __restrict__ outC)
{
    __shared__ u16 As[128][40];
    __shared__ u16 Bs[128][40];
    const int tid = threadIdx.x;
    const int GROUP = 8;
    int pid = blockIdx.x;
    int bpg = GROUP * GN;
    int group = pid / bpg;
    int first = group * GROUP;
    int gsz = min(GM - first, GROUP);
    int rem = pid - group * bpg;
    int bm = first + rem % gsz;
    int bn = rem / gsz;

    int MR = 0;
    if (MODE == 2) {
        MR = nrowsPtr[0];
        if (bm * 128 >= MR) return;   // compacted tail: nothing to do
    }

    const int w = tid >> 6, l = tid & 63;
    const int wr = (w >> 1) * 64, wc = (w & 1) * 64;
    const int lr = l & 15, lg = l >> 4;

    f32x4 acc[4][4] = {};

    for (int k0 = 0; k0 < K; k0 += 32) {
        __syncthreads();
        #pragma unroll
        for (int i = 0; i < 2; i++) {
            int L = tid * 8 + i * 2048;
            int r = L >> 5, c = L & 31;
            short8 v = {};
            int gr = bm * 128 + r;
            if (MODE != 2 || gr < MR) v = *(const short8*)&A[(size_t)gr * lda + k0 + c];
            *(short8*)&As[r][c] = v;
        }
        #pragma unroll
        for (int i = 0; i < 2; i++) {
            int L = tid * 8 + i * 2048;
            int r = L >> 5, c = L & 31;
            int gn = bn * 128 + r;
            short8 v = {};
            if (gn < Nreal) v = *(const short8*)&Bm[(size_t)gn * ldb + k0 + c];
            *(short8*)&Bs[r][c] = v;
        }
        __syncthreads();
        short8 af[4], bfr[4];
        #pragma unroll
        for (int m = 0; m < 4; m++) af[m] = *(const short8*)&As[wr + m * 16 + lr][lg * 8];
        #pragma unroll
        for (int n = 0; n < 4; n++) bfr[n] = *(const short8*)&Bs[wc + n * 16 + lr][lg * 8];
        #pragma unroll
        for (int m = 0; m < 4; m++)
            #pragma unroll
            for (int n = 0; n < 4; n++)
                acc[m][n] = __builtin_amdgcn_mfma_f32_16x16x32_bf16(af[m], bfr[n], acc[m][n], 0, 0, 0);
    }

    #pragma unroll
    for (int m = 0; m < 4; m++) {
        #pragma unroll
        for (int n = 0; n < 4; n++) {
            #pragma unroll
            for (int i = 0; i < 4; i++) {
                int row = bm * 128 + wr + m * 16 + lg * 4 + i;
                int col = bn * 128 + wc + n * 16 + lr;
                float v = acc[m][n][i];
                if (MODE == 0) {
                    outF[(size_t)row * 2048 + col] = v + bias[col];
                } else if (MODE == 1) {
                    if (col < 512) outH[row * 512 + col] = f2bf(v + bias[col]);
                    else outC[row * 512 + (col - 512)] = v + bias2[col - 512];
                } else {
                    if (row < MR && col < Nreal) {
                        int map = rowmap[row];
                        int b = map & 127, t = map >> 7;
                        outF[(size_t)b * ((size_t)TM * NV) + (size_t)t * NV + col] = v + bias[col];
                    }
                }
            }
        }
    }
}

// ---------------- persistent LSTM: all 49 steps in one kernel ----------------
// 64 WGs = 4 row-groups x 16 col-blocks. Wave (hi,lo) computes ALL 4 gates for its
// 16x16 (row x col) tile -> i/f/g/o for a given (row,col) land in the SAME lane,
// same reg index => fully lane-local epilogue, no LDS gate exchange, no gs barrier.
// h_old and c live in registers (producer thread is the same every step).
// Whh fragments (bq[4][16] = 256 VGPR) pinned via asm to prevent rematerialization.
__global__ __launch_bounds__(256, 1) void lstm_all(
    const u16* __restrict__ Whh, const float* __restrict__ X,
    u16* __restrict__ hb0, u16* __restrict__ hb1,
    const float* __restrict__ cf, u16* __restrict__ HnewC,
    const int* __restrict__ decl, unsigned* __restrict__ slots,
    const int* __restrict__ offs)
{
    __shared__ u16 As[32][520];       // h rows, full K=512, padded
    const int tid = threadIdx.x;
    const int wg = blockIdx.x;
    const int rb = wg >> 4, cb = wg & 15;
    const int w = tid >> 6, l = tid & 63;
    const int hi = w >> 1, lo = w & 1;
    const int lr = l & 15, lg = l >> 4;
    unsigned* gslots = slots + rb * 64;   // this group's 16 slots

    // this lane's output coords: col fixed, 4 rows (C/D layout: col=l&15, row=lg*4+i)
    const int col = cb * 32 + lo * 16 + lr;
    int rowg[4];
    #pragma unroll
    for (int i = 0; i < 4; i++) rowg[i] = rb * 32 + hi * 16 + lg * 4 + i;

    int edec[4];
    f32x4 creg;
    us4 hreg;
    #pragma unroll
    for (int i = 0; i < 4; i++) {
        edec[i] = decl[rowg[i]];
        creg[i] = cf[(size_t)rowg[i] * 512 + col];
        hreg[i] = hb0[(size_t)rowg[i] * 512 + col];
    }

    // Whh fragments for all 4 gates of this wave's 16-col slice, in registers
    short8 bq[4][16];
    #pragma unroll
    for (int q = 0; q < 4; q++) {
        const u16* base = &Whh[(size_t)(q * 512 + cb * 32 + lo * 16 + lr) * 512 + lg * 8];
        #pragma unroll
        for (int kk = 0; kk < 16; kk++)
            bq[q][kk] = *(const short8*)&base[kk * 32];
    }
    #pragma unroll
    for (int q = 0; q < 4; q++)
        #pragma unroll
        for (int kk = 0; kk < 16; kk++)
            asm volatile("" : "+v"(bq[q][kk]));   // pin: no remat of weight loads

    for (int t = 0; t < TM; t++) {
        const u16* hin = (t & 1) ? hb1 : hb0;
        u16* hout = (t & 1) ? hb0 : hb1;

        // prefetch X[t] gate addends (independent of h): x[q][i] for this lane
        const float* Xt = X + (size_t)t * 262144;
        float xq[4][4];
        #pragma unroll
        for (int q = 0; q < 4; q++)
            #pragma unroll
            for (int i = 0; i < 4; i++)
                xq[q][i] = Xt[(size_t)rowg[i] * 2048 + q * 512 + col];
        int offt = offs[t];

        // group-local barrier: wait until all 16 WGs of this row-group posted step t
        if (t > 0) {
            if (tid < 16) {
                while (__hip_atomic_load(&gslots[tid], __ATOMIC_RELAXED,
                                         __HIP_MEMORY_SCOPE_AGENT) < (unsigned)t)
                    __builtin_amdgcn_s_sleep(1);
            }
            __syncthreads();
        }

        // stage 32 rows x 512 cols of h into LDS via coherence-point atomic loads
        #pragma unroll
        for (int i = 0; i < 16; i++) {
            int L = i * 256 + tid;          // u64 index; 4096 total
            int r = L >> 7, cc = (L & 127) * 4;
            U64c u;
            u.u = __hip_atomic_load((const u64*)&hin[(size_t)(rb * 32 + r) * 512 + cc],
                                    __ATOMIC_RELAXED, __HIP_MEMORY_SCOPE_AGENT);
            *(us4*)&As[r][cc] = u.v;
        }
        __syncthreads();

        // 4 gates x 16 K-steps; A-frag shared across gates
        f32x4 acc[4] = {};
        #pragma unroll
        for (int kk = 0; kk < 16; kk++) {
            short8 a = *(const short8*)&As[hi * 16 + lr][kk * 32 + lg * 8];
            acc[0] = __builtin_amdgcn_mfma_f32_16x16x32_bf16(a, bq[0][kk], acc[0], 0, 0, 0);
            acc[1] = __builtin_amdgcn_mfma_f32_16x16x32_bf16(a, bq[1][kk], acc[1], 0, 0, 0);
            acc[2] = __builtin_amdgcn_mfma_f32_16x16x32_bf16(a, bq[2][kk], acc[2], 0, 0, 0);
            acc[3] = __builtin_amdgcn_mfma_f32_16x16x32_bf16(a, bq[3][kk], acc[3], 0, 0, 0);
        }

        // lane-local epilogue: 4 rows x 1 col per lane
        #pragma unroll
        for (int i = 0; i < 4; i++) {
            int act = (t < edec[i]);
            float iv = sigm(acc[0][i] + xq[0][i]);
            float fv = sigm(acc[1][i] + xq[1][i]);
            float gv = tanhf(acc[2][i] + xq[2][i]);
            float ov = sigm(acc[3][i] + xq[3][i]);
            float cn = fv * creg[i] + iv * gv;
            float hn_f = ov * tanhf(cn);
            if (act) {
                creg[i] = cn;
                hreg[i] = f2bf(hn_f);
                HnewC[(size_t)(offt + rowg[i]) * 512 + col] = f2bf(hn_f);
            }
            __hip_atomic_store(&hout[(size_t)rowg[i] * 512 + col], hreg[i],
                               __ATOMIC_RELAXED, __HIP_MEMORY_SCOPE_AGENT);
        }

        // drain stores (syncthreads implies vmcnt(0)), then post our slot
        __syncthreads();
        if (t < TM - 1 && tid == 0)
            __hip_atomic_store(&slots[rb * 64 + cb], (unsigned)(t + 1),
                               __ATOMIC_RELAXED, __HIP_MEMORY_SCOPE_AGENT);
    }
}

extern "C" void kernel_launch(void* const* d_in, const int* in_sizes, int n_in,
                              void* d_out, int out_size, void* d_ws, size_t ws_size,
                              hipStream_t stream) {
    const float* enc      = (const float*)d_in[0];
    const int*   captions = (const int*)d_in[1];
    const int*   caplens  = (const int*)d_in[2];
    const float* embW     = (const float*)d_in[3];
    const float* Wih      = (const float*)d_in[4];
    const float* Whh      = (const float*)d_in[5];
    const float* bih      = (const float*)d_in[6];
    const float* bhh      = (const float*)d_in[7];
    const float* fcW      = (const float*)d_in[8];
    const float* fcb      = (const float*)d_in[9];
    const float* ihW      = (const float*)d_in[10];
    const float* ihb      = (const float*)d_in[11];
    const float* icW      = (const float*)d_in[12];
    const float* icb      = (const float*)d_in[13];
    float* out = (float*)d_out;

    char* ws = (char*)d_ws;
    u16*   WihB = (u16*)(ws + 0);
    u16*   WhhB = (u16*)(ws + 2097152);
    u16*   fcWB = (u16*)(ws + 4194304);
    u16*   WhcB = (u16*)(ws + 14434304);
    u16*   encB = (u16*)(ws + 18628608);
    u16*   Xemb = (u16*)(ws + 19152896);
    float* X    = (float*)(ws + 25575424);
    u16*   HnewC= (u16*)(ws + 76955648);
    u16*   hb0  = (u16*)(ws + 83378176);
    u16*   hb1  = (u16*)(ws + 83509248);
    float* cf   = (float*)(ws + 83640320);
    int*   sidx = (int*)(ws + 83902464);
    int*   decl = (int*)(ws + 83902976);
    int*   capsS= (int*)(ws + 83903488);
    float* bsum = (float*)(ws + 83929088);
    unsigned* slots = (unsigned*)(ws + 83937280);   // 256 ints (4 groups x 64)
    int*   offs  = (int*)(ws + 83938304);           // 50 ints; offs[49] = nrowsC
    int*   rowmap= (int*)(ws + 83938560);           // 6272 ints

    k_sort<<<1, 128, 0, stream>>>(caplens, captions, bih, bhh, sidx, decl, capsS, bsum,
                                  out + 62720000, slots, offs, rowmap);
    k_zero<<<6272, 256, 0, stream>>>(decl, out);
    k_cvt<<<9096, 256, 0, stream>>>(Wih, Whh, fcW, ihW, icW, WihB, WhhB, fcWB, WhcB);
    k_gather<<<3392, 256, 0, stream>>>(enc, embW, sidx, capsS, encB, Xemb);
    // h0 | c0 : (128 x 1024) = encB (128x2048) @ WhcB^T
    gemm128<1><<<8, 256, 0, stream>>>(encB, 2048, WhcB, 2048, 1024, 2048, 1, 8,
                                      ihb, icb, nullptr, nullptr, nullptr, hb0, cf);
    // X = Xemb (6272x512) @ WihB^T (2048x512) + (b_ih+b_hh)
    gemm128<0><<<784, 256, 0, stream>>>(Xemb, 512, WihB, 512, 2048, 512, 49, 16,
                                        bsum, nullptr, nullptr, nullptr, X, nullptr, nullptr);
    // all 49 LSTM steps in one persistent kernel (writes compacted Hnew)
    lstm_all<<<NWG, 256, 0, stream>>>(WhhB, X, hb0, hb1, cf, HnewC, decl, slots, offs);
    // predictions = HnewC (nrowsC x 512) @ fcWB^T (10000x512) + fc_b, rowmap scatter
    gemm128<2><<<3871, 256, 0, stream>>>(HnewC, 512, fcWB, 512, NV, 512, 49, 79,
                                         fcb, nullptr, offs + 49, rowmap, out, nullptr, nullptr);
}

// Round 8
// 533.264 us; speedup vs baseline: 1.2481x; 1.2481x over previous
//
#include <hip/hip_runtime.h>
#include <hip/hip_bf16.h>
#include <math.h>

typedef __attribute__((ext_vector_type(8))) short short8;
typedef __attribute__((ext_vector_type(4))) float f32x4;
typedef __attribute__((ext_vector_type(4))) unsigned short us4;
typedef unsigned short u16;
typedef unsigned long long u64;

#define TM 49
#define NV 10000
#define NWG 64

union U64c { us4 v; u64 u; };

__device__ __forceinline__ u16 f2bf(float f) {
    union { float f; unsigned u; } v; v.f = f;
    unsigned r = v.u + 0x7fffu + ((v.u >> 16) & 1u);
    return (u16)(r >> 16);
}
__device__ __forceinline__ float bf2f(u16 b) {
    union { unsigned u; float f; } v; v.u = ((unsigned)b) << 16;
    return v.f;
}
__device__ __forceinline__ float sigm(float x) { return 1.0f / (1.0f + expf(-x)); }

// coherence-point access helpers (sc0 sc1 = bypass L1+L2; plain vmcnt-counted ops,
// unlike __hip_atomic_* which hipcc serializes with per-op waits)
__device__ __forceinline__ u64 ld_cp64(const u16* p) {
    u64 r;
    asm volatile("global_load_dwordx2 %0, %1, off sc0 sc1" : "=v"(r) : "v"(p));
    return r;   // caller must s_waitcnt before use
}
__device__ __forceinline__ void st_cp16(u16* p, unsigned v) {
    asm volatile("global_store_short %0, %1, off sc0 sc1" :: "v"(p), "v"(v) : "memory");
}
__device__ __forceinline__ unsigned ld_cp32_wait(const unsigned* p) {
    unsigned r;
    asm volatile("global_load_dword %0, %1, off sc0 sc1\n\ts_waitcnt vmcnt(0)"
                 : "=v"(r) : "v"(p) : "memory");
    return r;
}

// ---------------- sort + metadata + compaction tables + small outputs ----------------
__global__ __launch_bounds__(128) void k_sort(
    const int* __restrict__ caplens, const int* __restrict__ captions,
    const float* __restrict__ bih, const float* __restrict__ bhh,
    int* __restrict__ sidx, int* __restrict__ decl, int* __restrict__ capsS,
    float* __restrict__ bsum, float* __restrict__ out_tail,
    unsigned* __restrict__ slots, int* __restrict__ offs, int* __restrict__ rowmap)
{
    __shared__ int s_cl[128];
    __shared__ int s_si[128];
    __shared__ int s_dl[128];
    __shared__ int s_n[49];
    __shared__ int s_off[50];
    int tid = threadIdx.x;
    for (int k = tid; k < 256; k += 128)   // reset per-group counters
        __hip_atomic_store(&slots[k], 0u, __ATOMIC_RELAXED, __HIP_MEMORY_SCOPE_AGENT);
    int my = caplens[tid];
    s_cl[tid] = my;
    __syncthreads();
    int r = 0;
    for (int j = 0; j < 128; j++) {
        int cj = s_cl[j];
        if (cj > my || (cj == my && j < tid)) r++;
    }
    s_si[r] = tid;   // stable descending argsort
    __syncthreads();
    int src = s_si[tid];
    sidx[tid] = src;
    int dl = s_cl[src] - 1;
    decl[tid] = dl;
    s_dl[tid] = dl;
    out_tail[6400 + tid] = (float)dl;
    out_tail[6528 + tid] = (float)src;
    for (int t = 0; t < 50; t++) {
        int tok = captions[src * 50 + t];
        capsS[tid * 50 + t] = tok;
        out_tail[tid * 50 + t] = (float)tok;
    }
    for (int k = tid; k < 2048; k += 128) bsum[k] = bih[k] + bhh[k];
    __syncthreads();
    if (tid < 49) {
        int c = 0;
        for (int b = 0; b < 128; b++) c += (s_dl[b] > tid);
        s_n[tid] = c;
    }
    __syncthreads();
    if (tid == 0) {
        int a = 0;
        for (int t = 0; t < 49; t++) { s_off[t] = a; a += s_n[t]; }
        s_off[49] = a;   // total compacted rows
    }
    __syncthreads();
    if (tid < 50) offs[tid] = s_off[tid];
    for (int t = 0; t < dl; t++) rowmap[s_off[t] + tid] = t * 128 + tid;
}

// ---------------- zero-fill masked prediction rows ----------------
__global__ __launch_bounds__(256) void k_zero(
    const int* __restrict__ decl, float* __restrict__ out)
{
    int r = blockIdx.x;           // 0..6271
    int b = r / 49, t = r - b * 49;
    if (t < decl[b]) return;
    float* dst = out + (size_t)b * 490000 + (size_t)t * 10000;
    f32x4 z = {};
    for (int i = threadIdx.x; i < 2500; i += 256) *(f32x4*)&dst[i * 4] = z;
}

// ---------------- weight fp32 -> bf16 conversion ----------------
__global__ __launch_bounds__(256) void k_cvt(
    const float* __restrict__ Wih, const float* __restrict__ Whh,
    const float* __restrict__ fcW, const float* __restrict__ ihW,
    const float* __restrict__ icW,
    u16* __restrict__ WihB, u16* __restrict__ WhhB,
    u16* __restrict__ fcWB, u16* __restrict__ WhcB)
{
    int idx = blockIdx.x * 256 + threadIdx.x;  // float4 index, exact grid
    const float* src; u16* dst; int o;
    if (idx < 262144)        { src = Wih; dst = WihB; o = idx; }
    else if (idx < 524288)   { src = Whh; dst = WhhB; o = idx - 262144; }
    else if (idx < 1804288)  { src = fcW; dst = fcWB; o = idx - 524288; }
    else if (idx < 2066432)  { src = ihW; dst = WhcB; o = idx - 1804288; }
    else                     { src = icW; dst = WhcB + 1048576; o = idx - 2066432; }
    f32x4 v = *(const f32x4*)&src[(size_t)o * 4];
    us4 b = { f2bf(v.x), f2bf(v.y), f2bf(v.z), f2bf(v.w) };
    *(us4*)&dst[(size_t)o * 4] = b;
}

// ---------------- gathers: sorted enc -> bf16, embedding -> bf16 ----------------
__global__ __launch_bounds__(256) void k_gather(
    const float* __restrict__ enc, const float* __restrict__ embW,
    const int* __restrict__ sidx, const int* __restrict__ capsS,
    u16* __restrict__ encB, u16* __restrict__ Xemb)
{
    int idx = blockIdx.x * 256 + threadIdx.x;
    if (idx < 65536) {
        int b = idx >> 9, k4 = idx & 511;
        f32x4 v = *(const f32x4*)&enc[(size_t)sidx[b] * 2048 + k4 * 4];
        us4 o = { f2bf(v.x), f2bf(v.y), f2bf(v.z), f2bf(v.w) };
        *(us4*)&encB[(size_t)b * 2048 + k4 * 4] = o;
    } else {
        int j = idx - 65536;              // < 802816
        int row = j >> 7, k4 = j & 127;   // row = t*128 + b
        int t = row >> 7, b = row & 127;
        int tok = capsS[b * 50 + t];
        f32x4 v = *(const f32x4*)&embW[(size_t)tok * 512 + k4 * 4];
        us4 o = { f2bf(v.x), f2bf(v.y), f2bf(v.z), f2bf(v.w) };
        *(us4*)&Xemb[(size_t)row * 512 + k4 * 4] = o;
    }
}

// ---------------- generic 128x128 bf16 MFMA GEMM, C = A * B^T ----------------
template<int MODE>
__global__ __launch_bounds__(256) void gemm128(
    const u16* __restrict__ A, int lda,
    const u16* __restrict__ Bm, int ldb, int Nreal, int K,
    int GM, int GN,
    const float* __restrict__ bias, const float* __restrict__ bias2,
    const int* __restrict__ nrowsPtr, const int* __restrict__ rowmap,
    float* __restrict__ outF, u16* __restrict__ outH, float* __restrict__ outC)
{
    __shared__ u16 As[128][40];
    __shared__ u16 Bs[128][40];
    const int tid = threadIdx.x;
    const int GROUP = 8;
    int pid = blockIdx.x;
    int bpg = GROUP * GN;
    int group = pid / bpg;
    int first = group * GROUP;
    int gsz = min(GM - first, GROUP);
    int rem = pid - group * bpg;
    int bm = first + rem % gsz;
    int bn = rem / gsz;

    int MR = 0;
    if (MODE == 2) {
        MR = nrowsPtr[0];
        if (bm * 128 >= MR) return;   // compacted tail: nothing to do
    }

    const int w = tid >> 6, l = tid & 63;
    const int wr = (w >> 1) * 64, wc = (w & 1) * 64;
    const int lr = l & 15, lg = l >> 4;

    f32x4 acc[4][4] = {};

    for (int k0 = 0; k0 < K; k0 += 32) {
        __syncthreads();
        #pragma unroll
        for (int i = 0; i < 2; i++) {
            int L = tid * 8 + i * 2048;
            int r = L >> 5, c = L & 31;
            short8 v = {};
            int gr = bm * 128 + r;
            if (MODE != 2 || gr < MR) v = *(const short8*)&A[(size_t)gr * lda + k0 + c];
            *(short8*)&As[r][c] = v;
        }
        #pragma unroll
        for (int i = 0; i < 2; i++) {
            int L = tid * 8 + i * 2048;
            int r = L >> 5, c = L & 31;
            int gn = bn * 128 + r;
            short8 v = {};
            if (gn < Nreal) v = *(const short8*)&Bm[(size_t)gn * ldb + k0 + c];
            *(short8*)&Bs[r][c] = v;
        }
        __syncthreads();
        short8 af[4], bfr[4];
        #pragma unroll
        for (int m = 0; m < 4; m++) af[m] = *(const short8*)&As[wr + m * 16 + lr][lg * 8];
        #pragma unroll
        for (int n = 0; n < 4; n++) bfr[n] = *(const short8*)&Bs[wc + n * 16 + lr][lg * 8];
        #pragma unroll
        for (int m = 0; m < 4; m++)
            #pragma unroll
            for (int n = 0; n < 4; n++)
                acc[m][n] = __builtin_amdgcn_mfma_f32_16x16x32_bf16(af[m], bfr[n], acc[m][n], 0, 0, 0);
    }

    #pragma unroll
    for (int m = 0; m < 4; m++) {
        #pragma unroll
        for (int n = 0; n < 4; n++) {
            #pragma unroll
            for (int i = 0; i < 4; i++) {
                int row = bm * 128 + wr + m * 16 + lg * 4 + i;
                int col = bn * 128 + wc + n * 16 + lr;
                float v = acc[m][n][i];
                if (MODE == 0) {
                    outF[(size_t)row * 2048 + col] = v + bias[col];
                } else if (MODE == 1) {
                    if (col < 512) outH[row * 512 + col] = f2bf(v + bias[col]);
                    else outC[row * 512 + (col - 512)] = v + bias2[col - 512];
                } else {
                    if (row < MR && col < Nreal) {
                        int map = rowmap[row];
                        int b = map & 127, t = map >> 7;
                        outF[(size_t)b * ((size_t)TM * NV) + (size_t)t * NV + col] = v + bias[col];
                    }
                }
            }
        }
    }
}

// ---------------- persistent LSTM: all 49 steps in one kernel ----------------
// 64 WGs = 4 row-groups x 16 col-blocks. h exchange via sc0sc1 (coherence-point)
// asm loads/stores: 16 loads issued back-to-back, ONE vmcnt drain (pipelined, vs
// hipcc's serialized atomics). Group barrier = one memory-side atomic counter.
__global__ __launch_bounds__(256, 1) void lstm_all(
    const u16* __restrict__ Whh, const float* __restrict__ X,
    u16* __restrict__ hb0, u16* __restrict__ hb1,
    const float* __restrict__ cf, u16* __restrict__ HnewC,
    const int* __restrict__ decl, unsigned* __restrict__ slots,
    const int* __restrict__ offs)
{
    __shared__ u16 As[32][520];       // h rows, full K=512, padded
    const int tid = threadIdx.x;
    const int wg = blockIdx.x;
    const int rb = wg >> 4, cb = wg & 15;
    const int w = tid >> 6, l = tid & 63;
    const int hi = w >> 1, lo = w & 1;
    const int lr = l & 15, lg = l >> 4;
    unsigned* cnt = slots + rb * 32;   // this row-group's counter (128B apart)

    // this lane's output coords: col fixed, 4 rows (C/D layout: col=l&15, row=lg*4+i)
    const int col = cb * 32 + lo * 16 + lr;
    int rowg[4];
    #pragma unroll
    for (int i = 0; i < 4; i++) rowg[i] = rb * 32 + hi * 16 + lg * 4 + i;

    int edec[4];
    f32x4 creg;
    us4 hreg;
    #pragma unroll
    for (int i = 0; i < 4; i++) {
        edec[i] = decl[rowg[i]];
        creg[i] = cf[(size_t)rowg[i] * 512 + col];
        hreg[i] = hb0[(size_t)rowg[i] * 512 + col];
    }

    // Whh fragments for all 4 gates of this wave's 16-col slice, in registers
    short8 bq[4][16];
    #pragma unroll
    for (int q = 0; q < 4; q++) {
        const u16* base = &Whh[(size_t)(q * 512 + cb * 32 + lo * 16 + lr) * 512 + lg * 8];
        #pragma unroll
        for (int kk = 0; kk < 16; kk++)
            bq[q][kk] = *(const short8*)&base[kk * 32];
    }
    #pragma unroll
    for (int q = 0; q < 4; q++)
        #pragma unroll
        for (int kk = 0; kk < 16; kk++)
            asm volatile("" : "+v"(bq[q][kk]));   // pin: no remat of weight loads

    for (int t = 0; t < TM; t++) {
        const u16* hin = (t & 1) ? hb1 : hb0;
        u16* hout = (t & 1) ? hb0 : hb1;

        // prefetch X[t] gate addends (independent of h)
        const float* Xt = X + (size_t)t * 262144;
        float xq[4][4];
        #pragma unroll
        for (int q = 0; q < 4; q++)
            #pragma unroll
            for (int i = 0; i < 4; i++)
                xq[q][i] = Xt[(size_t)rowg[i] * 2048 + q * 512 + col];
        int offt = offs[t];

        // group barrier: wait until all 16 WGs of this row-group posted step t
        if (t > 0) {
            if (tid == 0) {
                unsigned tgt = 16u * (unsigned)t;
                while (ld_cp32_wait(cnt) < tgt) __builtin_amdgcn_s_sleep(1);
            }
            __syncthreads();
        }

        // stage 32x512 h tile: 16 pipelined sc0sc1 loads, one drain, LDS writes
        U64c tmp[16];
        #pragma unroll
        for (int i = 0; i < 16; i++) {
            int L = i * 256 + tid;          // u64 index; 4096 total
            int r = L >> 7, cc = (L & 127) * 4;
            tmp[i].u = ld_cp64(&hin[(size_t)(rb * 32 + r) * 512 + cc]);
        }
        asm volatile("s_waitcnt vmcnt(0)" ::: "memory");
        __builtin_amdgcn_sched_barrier(0);
        #pragma unroll
        for (int i = 0; i < 16; i++) {
            int L = i * 256 + tid;
            int r = L >> 7, cc = (L & 127) * 4;
            *(us4*)&As[r][cc] = tmp[i].v;
        }
        __syncthreads();

        // 4 gates x 16 K-steps; A-frag shared across gates
        f32x4 acc[4] = {};
        #pragma unroll
        for (int kk = 0; kk < 16; kk++) {
            short8 a = *(const short8*)&As[hi * 16 + lr][kk * 32 + lg * 8];
            acc[0] = __builtin_amdgcn_mfma_f32_16x16x32_bf16(a, bq[0][kk], acc[0], 0, 0, 0);
            acc[1] = __builtin_amdgcn_mfma_f32_16x16x32_bf16(a, bq[1][kk], acc[1], 0, 0, 0);
            acc[2] = __builtin_amdgcn_mfma_f32_16x16x32_bf16(a, bq[2][kk], acc[2], 0, 0, 0);
            acc[3] = __builtin_amdgcn_mfma_f32_16x16x32_bf16(a, bq[3][kk], acc[3], 0, 0, 0);
        }

        // lane-local epilogue: 4 rows x 1 col per lane; h stores on critical path
        #pragma unroll
        for (int i = 0; i < 4; i++) {
            int act = (t < edec[i]);
            float iv = sigm(acc[0][i] + xq[0][i]);
            float fv = sigm(acc[1][i] + xq[1][i]);
            float gv = tanhf(acc[2][i] + xq[2][i]);
            float ov = sigm(acc[3][i] + xq[3][i]);
            float cn = fv * creg[i] + iv * gv;
            float hn_f = ov * tanhf(cn);
            if (act) {
                creg[i] = cn;
                hreg[i] = f2bf(hn_f);
            }
            st_cp16(&hout[(size_t)rowg[i] * 512 + col], (unsigned)hreg[i]);
        }

        // drain h stores, then post; HnewC writes AFTER the post (off critical path)
        asm volatile("s_waitcnt vmcnt(0)" ::: "memory");
        __syncthreads();
        if (t < TM - 1 && tid == 0) atomicAdd(cnt, 1u);

        #pragma unroll
        for (int i = 0; i < 4; i++)
            if (t < edec[i])
                HnewC[(size_t)(offt + rowg[i]) * 512 + col] = hreg[i];
    }
}

extern "C" void kernel_launch(void* const* d_in, const int* in_sizes, int n_in,
                              void* d_out, int out_size, void* d_ws, size_t ws_size,
                              hipStream_t stream) {
    const float* enc      = (const float*)d_in[0];
    const int*   captions = (const int*)d_in[1];
    const int*   caplens  = (const int*)d_in[2];
    const float* embW     = (const float*)d_in[3];
    const float* Wih      = (const float*)d_in[4];
    const float* Whh      = (const float*)d_in[5];
    const float* bih      = (const float*)d_in[6];
    const float* bhh      = (const float*)d_in[7];
    const float* fcW      = (const float*)d_in[8];
    const float* fcb      = (const float*)d_in[9];
    const float* ihW      = (const float*)d_in[10];
    const float* ihb      = (const float*)d_in[11];
    const float* icW      = (const float*)d_in[12];
    const float* icb      = (const float*)d_in[13];
    float* out = (float*)d_out;

    char* ws = (char*)d_ws;
    u16*   WihB = (u16*)(ws + 0);
    u16*   WhhB = (u16*)(ws + 2097152);
    u16*   fcWB = (u16*)(ws + 4194304);
    u16*   WhcB = (u16*)(ws + 14434304);
    u16*   encB = (u16*)(ws + 18628608);
    u16*   Xemb = (u16*)(ws + 19152896);
    float* X    = (float*)(ws + 25575424);
    u16*   HnewC= (u16*)(ws + 76955648);
    u16*   hb0  = (u16*)(ws + 83378176);
    u16*   hb1  = (u16*)(ws + 83509248);
    float* cf   = (float*)(ws + 83640320);
    int*   sidx = (int*)(ws + 83902464);
    int*   decl = (int*)(ws + 83902976);
    int*   capsS= (int*)(ws + 83903488);
    float* bsum = (float*)(ws + 83929088);
    unsigned* slots = (unsigned*)(ws + 83937280);   // 256 ints (4 groups x 32-stride)
    int*   offs  = (int*)(ws + 83938304);           // 50 ints; offs[49] = nrowsC
    int*   rowmap= (int*)(ws + 83938560);           // 6272 ints

    k_sort<<<1, 128, 0, stream>>>(caplens, captions, bih, bhh, sidx, decl, capsS, bsum,
                                  out + 62720000, slots, offs, rowmap);
    k_zero<<<6272, 256, 0, stream>>>(decl, out);
    k_cvt<<<9096, 256, 0, stream>>>(Wih, Whh, fcW, ihW, icW, WihB, WhhB, fcWB, WhcB);
    k_gather<<<3392, 256, 0, stream>>>(enc, embW, sidx, capsS, encB, Xemb);
    // h0 | c0 : (128 x 1024) = encB (128x2048) @ WhcB^T
    gemm128<1><<<8, 256, 0, stream>>>(encB, 2048, WhcB, 2048, 1024, 2048, 1, 8,
                                      ihb, icb, nullptr, nullptr, nullptr, hb0, cf);
    // X = Xemb (6272x512) @ WihB^T (2048x512) + (b_ih+b_hh)
    gemm128<0><<<784, 256, 0, stream>>>(Xemb, 512, WihB, 512, 2048, 512, 49, 16,
                                        bsum, nullptr, nullptr, nullptr, X, nullptr, nullptr);
    // all 49 LSTM steps in one persistent kernel (writes compacted Hnew)
    lstm_all<<<NWG, 256, 0, stream>>>(WhhB, X, hb0, hb1, cf, HnewC, decl, slots, offs);
    // predictions = HnewC (nrowsC x 512) @ fcWB^T (10000x512) + fc_b, rowmap scatter
    gemm128<2><<<3871, 256, 0, stream>>>(HnewC, 512, fcWB, 512, NV, 512, 49, 79,
                                         fcb, nullptr, offs + 49, rowmap, out, nullptr, nullptr);
}

// Round 9
// 472.428 us; speedup vs baseline: 1.4088x; 1.1288x over previous
//
#include <hip/hip_runtime.h>
#include <hip/hip_bf16.h>
#include <math.h>

typedef __attribute__((ext_vector_type(8))) short short8;
typedef __attribute__((ext_vector_type(4))) float f32x4;
typedef __attribute__((ext_vector_type(4))) unsigned short us4;
typedef unsigned short u16;
typedef unsigned long long u64;

#define TM 49
#define NV 10000
#define NLSTM 64
#define NFC 192
#define SMEM_BYTES 86016

union U64c { us4 v; u64 u; };

__device__ __forceinline__ u16 f2bf(float f) {
    union { float f; unsigned u; } v; v.f = f;
    unsigned r = v.u + 0x7fffu + ((v.u >> 16) & 1u);
    return (u16)(r >> 16);
}
__device__ __forceinline__ float bf2f(u16 b) {
    union { unsigned u; float f; } v; v.u = ((unsigned)b) << 16;
    return v.f;
}
__device__ __forceinline__ float sigm(float x) { return 1.0f / (1.0f + expf(-x)); }

// coherence-point access helpers (sc0 sc1 = bypass L1+L2, device coherence point)
__device__ __forceinline__ u64 ld_cp64(const u16* p) {
    u64 r;
    asm volatile("global_load_dwordx2 %0, %1, off sc0 sc1" : "=v"(r) : "v"(p));
    return r;   // caller must s_waitcnt before use
}
__device__ __forceinline__ short8 ld_cp128(const u16* p) {
    short8 r;
    asm volatile("global_load_dwordx4 %0, %1, off sc0 sc1" : "=v"(r) : "v"(p));
    return r;   // caller must s_waitcnt before use
}
__device__ __forceinline__ void st_cp16(u16* p, unsigned v) {
    asm volatile("global_store_short %0, %1, off sc0 sc1" :: "v"(p), "v"(v) : "memory");
}
__device__ __forceinline__ unsigned ld_cp32_wait(const unsigned* p) {
    unsigned r;
    asm volatile("global_load_dword %0, %1, off sc0 sc1\n\ts_waitcnt vmcnt(0)"
                 : "=v"(r) : "v"(p) : "memory");
    return r;
}

// ---------------- sort + metadata + compaction tables + small outputs ----------------
__global__ __launch_bounds__(128) void k_sort(
    const int* __restrict__ caplens, const int* __restrict__ captions,
    const float* __restrict__ bih, const float* __restrict__ bhh,
    int* __restrict__ sidx, int* __restrict__ decl, int* __restrict__ capsS,
    float* __restrict__ bsum, float* __restrict__ out_tail,
    unsigned* __restrict__ slots, int* __restrict__ offs, int* __restrict__ rowmap)
{
    __shared__ int s_cl[128];
    __shared__ int s_si[128];
    __shared__ int s_dl[128];
    __shared__ int s_n[49];
    __shared__ int s_off[50];
    int tid = threadIdx.x;
    for (int k = tid; k < 256; k += 128)   // reset per-group counters
        __hip_atomic_store(&slots[k], 0u, __ATOMIC_RELAXED, __HIP_MEMORY_SCOPE_AGENT);
    int my = caplens[tid];
    s_cl[tid] = my;
    __syncthreads();
    int r = 0;
    for (int j = 0; j < 128; j++) {
        int cj = s_cl[j];
        if (cj > my || (cj == my && j < tid)) r++;
    }
    s_si[r] = tid;   // stable descending argsort
    __syncthreads();
    int src = s_si[tid];
    sidx[tid] = src;
    int dl = s_cl[src] - 1;
    decl[tid] = dl;
    s_dl[tid] = dl;
    out_tail[6400 + tid] = (float)dl;
    out_tail[6528 + tid] = (float)src;
    for (int t = 0; t < 50; t++) {
        int tok = captions[src * 50 + t];
        capsS[tid * 50 + t] = tok;
        out_tail[tid * 50 + t] = (float)tok;
    }
    for (int k = tid; k < 2048; k += 128) bsum[k] = bih[k] + bhh[k];
    __syncthreads();
    if (tid < 49) {
        int c = 0;
        for (int b = 0; b < 128; b++) c += (s_dl[b] > tid);
        s_n[tid] = c;
    }
    __syncthreads();
    if (tid == 0) {
        int a = 0;
        for (int t = 0; t < 49; t++) { s_off[t] = a; a += s_n[t]; }
        s_off[49] = a;   // total compacted rows
    }
    __syncthreads();
    if (tid < 50) offs[tid] = s_off[tid];
    for (int t = 0; t < dl; t++) rowmap[s_off[t] + tid] = t * 128 + tid;
}

// ---------------- zero-fill masked prediction rows ----------------
__global__ __launch_bounds__(256) void k_zero(
    const int* __restrict__ decl, float* __restrict__ out)
{
    int r = blockIdx.x;           // 0..6271
    int b = r / 49, t = r - b * 49;
    if (t < decl[b]) return;
    float* dst = out + (size_t)b * 490000 + (size_t)t * 10000;
    f32x4 z = {};
    for (int i = threadIdx.x; i < 2500; i += 256) *(f32x4*)&dst[i * 4] = z;
}

// ---------------- weight fp32 -> bf16 conversion ----------------
__global__ __launch_bounds__(256) void k_cvt(
    const float* __restrict__ Wih, const float* __restrict__ Whh,
    const float* __restrict__ fcW, const float* __restrict__ ihW,
    const float* __restrict__ icW,
    u16* __restrict__ WihB, u16* __restrict__ WhhB,
    u16* __restrict__ fcWB, u16* __restrict__ WhcB)
{
    int idx = blockIdx.x * 256 + threadIdx.x;  // float4 index, exact grid
    const float* src; u16* dst; int o;
    if (idx < 262144)        { src = Wih; dst = WihB; o = idx; }
    else if (idx < 524288)   { src = Whh; dst = WhhB; o = idx - 262144; }
    else if (idx < 1804288)  { src = fcW; dst = fcWB; o = idx - 524288; }
    else if (idx < 2066432)  { src = ihW; dst = WhcB; o = idx - 1804288; }
    else                     { src = icW; dst = WhcB + 1048576; o = idx - 2066432; }
    f32x4 v = *(const f32x4*)&src[(size_t)o * 4];
    us4 b = { f2bf(v.x), f2bf(v.y), f2bf(v.z), f2bf(v.w) };
    *(us4*)&dst[(size_t)o * 4] = b;
}

// ---------------- gathers: sorted enc -> bf16, embedding -> bf16 ----------------
__global__ __launch_bounds__(256) void k_gather(
    const float* __restrict__ enc, const float* __restrict__ embW,
    const int* __restrict__ sidx, const int* __restrict__ capsS,
    u16* __restrict__ encB, u16* __restrict__ Xemb)
{
    int idx = blockIdx.x * 256 + threadIdx.x;
    if (idx < 65536) {
        int b = idx >> 9, k4 = idx & 511;
        f32x4 v = *(const f32x4*)&enc[(size_t)sidx[b] * 2048 + k4 * 4];
        us4 o = { f2bf(v.x), f2bf(v.y), f2bf(v.z), f2bf(v.w) };
        *(us4*)&encB[(size_t)b * 2048 + k4 * 4] = o;
    } else {
        int j = idx - 65536;              // < 802816
        int row = j >> 7, k4 = j & 127;   // row = t*128 + b
        int t = row >> 7, b = row & 127;
        int tok = capsS[b * 50 + t];
        f32x4 v = *(const f32x4*)&embW[(size_t)tok * 512 + k4 * 4];
        us4 o = { f2bf(v.x), f2bf(v.y), f2bf(v.z), f2bf(v.w) };
        *(us4*)&Xemb[(size_t)row * 512 + k4 * 4] = o;
    }
}

// ---------------- generic 128x128 bf16 MFMA GEMM, C = A * B^T (modes 0,1) --------
template<int MODE>
__global__ __launch_bounds__(256) void gemm128(
    const u16* __restrict__ A, int lda,
    const u16* __restrict__ Bm, int ldb, int Nreal, int K,
    int GM, int GN,
    const float* __restrict__ bias, const float* __restrict__ bias2,
    float* __restrict__ outF, u16* __restrict__ outH, float* __restrict__ outC)
{
    __shared__ u16 As[128][40];
    __shared__ u16 Bs[128][40];
    const int tid = threadIdx.x;
    const int GROUP = 8;
    int pid = blockIdx.x;
    int bpg = GROUP * GN;
    int group = pid / bpg;
    int first = group * GROUP;
    int gsz = min(GM - first, GROUP);
    int rem = pid - group * bpg;
    int bm = first + rem % gsz;
    int bn = rem / gsz;

    const int w = tid >> 6, l = tid & 63;
    const int wr = (w >> 1) * 64, wc = (w & 1) * 64;
    const int lr = l & 15, lg = l >> 4;

    f32x4 acc[4][4] = {};

    for (int k0 = 0; k0 < K; k0 += 32) {
        __syncthreads();
        #pragma unroll
        for (int i = 0; i < 2; i++) {
            int L = tid * 8 + i * 2048;
            int r = L >> 5, c = L & 31;
            short8 v = *(const short8*)&A[(size_t)(bm * 128 + r) * lda + k0 + c];
            *(short8*)&As[r][c] = v;
        }
        #pragma unroll
        for (int i = 0; i < 2; i++) {
            int L = tid * 8 + i * 2048;
            int r = L >> 5, c = L & 31;
            int gn = bn * 128 + r;
            short8 v = {};
            if (gn < Nreal) v = *(const short8*)&Bm[(size_t)gn * ldb + k0 + c];
            *(short8*)&Bs[r][c] = v;
        }
        __syncthreads();
        short8 af[4], bfr[4];
        #pragma unroll
        for (int m = 0; m < 4; m++) af[m] = *(const short8*)&As[wr + m * 16 + lr][lg * 8];
        #pragma unroll
        for (int n = 0; n < 4; n++) bfr[n] = *(const short8*)&Bs[wc + n * 16 + lr][lg * 8];
        #pragma unroll
        for (int m = 0; m < 4; m++)
            #pragma unroll
            for (int n = 0; n < 4; n++)
                acc[m][n] = __builtin_amdgcn_mfma_f32_16x16x32_bf16(af[m], bfr[n], acc[m][n], 0, 0, 0);
    }

    #pragma unroll
    for (int m = 0; m < 4; m++) {
        #pragma unroll
        for (int n = 0; n < 4; n++) {
            #pragma unroll
            for (int i = 0; i < 4; i++) {
                int row = bm * 128 + wr + m * 16 + lg * 4 + i;
                int col = bn * 128 + wc + n * 16 + lr;
                float v = acc[m][n][i];
                if (MODE == 0) {
                    outF[(size_t)row * 2048 + col] = v + bias[col];
                } else {
                    if (col < 512) outH[row * 512 + col] = f2bf(v + bias[col]);
                    else outC[row * 512 + (col - 512)] = v + bias2[col - 512];
                }
            }
        }
    }
}

// ---------------- fused persistent kernel: LSTM recurrence + fc GEMM consumers ----
// blocks 0..63:   recurrence producers (round-8 protocol; HnewC sc0sc1 before drain,
//                 counter posted every step).
// blocks 64..255: fc consumers; 128x128 prediction tiles gated on the 4 group
//                 counters; A staged from HnewC via sc0sc1; rowmap scatter + bias.
// Dynamic LDS 84KB forces 1 WG/CU. Dependency is one-way -> no deadlock.
__global__ __launch_bounds__(256, 1) void lstm_fc(
    const u16* __restrict__ Whh, const float* __restrict__ X,
    u16* __restrict__ hb0, u16* __restrict__ hb1,
    const float* __restrict__ cf, u16* __restrict__ HnewC,
    const int* __restrict__ decl, unsigned* __restrict__ slots,
    const int* __restrict__ offs, const int* __restrict__ rowmap,
    const u16* __restrict__ fcWB, const float* __restrict__ fcb,
    float* __restrict__ out)
{
    extern __shared__ char smem[];
    const int tid = threadIdx.x;
    const int wg = blockIdx.x;

    if (wg < NLSTM) {
        // ======================= recurrence producer =======================
        u16 (*As)[520] = (u16(*)[520])smem;   // 32 x 520 u16 = 33280 B
        const int rb = wg >> 4, cb = wg & 15;
        const int w = tid >> 6, l = tid & 63;
        const int hi = w >> 1, lo = w & 1;
        const int lr = l & 15, lg = l >> 4;
        unsigned* cnt = slots + rb * 32;

        const int col = cb * 32 + lo * 16 + lr;
        int rowg[4];
        #pragma unroll
        for (int i = 0; i < 4; i++) rowg[i] = rb * 32 + hi * 16 + lg * 4 + i;

        int edec[4];
        f32x4 creg;
        us4 hreg;
        #pragma unroll
        for (int i = 0; i < 4; i++) {
            edec[i] = decl[rowg[i]];
            creg[i] = cf[(size_t)rowg[i] * 512 + col];
            hreg[i] = hb0[(size_t)rowg[i] * 512 + col];
        }

        short8 bq[4][16];
        #pragma unroll
        for (int q = 0; q < 4; q++) {
            const u16* base = &Whh[(size_t)(q * 512 + cb * 32 + lo * 16 + lr) * 512 + lg * 8];
            #pragma unroll
            for (int kk = 0; kk < 16; kk++)
                bq[q][kk] = *(const short8*)&base[kk * 32];
        }
        #pragma unroll
        for (int q = 0; q < 4; q++)
            #pragma unroll
            for (int kk = 0; kk < 16; kk++)
                asm volatile("" : "+v"(bq[q][kk]));   // pin: no remat of weight loads

        for (int t = 0; t < TM; t++) {
            const u16* hin = (t & 1) ? hb1 : hb0;
            u16* hout = (t & 1) ? hb0 : hb1;

            const float* Xt = X + (size_t)t * 262144;
            float xq[4][4];
            #pragma unroll
            for (int q = 0; q < 4; q++)
                #pragma unroll
                for (int i = 0; i < 4; i++)
                    xq[q][i] = Xt[(size_t)rowg[i] * 2048 + q * 512 + col];
            int offt = offs[t];

            if (t > 0) {
                if (tid == 0) {
                    unsigned tgt = 16u * (unsigned)t;
                    while (ld_cp32_wait(cnt) < tgt) __builtin_amdgcn_s_sleep(1);
                }
                __syncthreads();
            }

            // stage 32x512 h tile: 16 pipelined sc0sc1 loads, one drain, LDS writes
            U64c tmp[16];
            #pragma unroll
            for (int i = 0; i < 16; i++) {
                int L = i * 256 + tid;          // u64 index; 4096 total
                int r = L >> 7, cc = (L & 127) * 4;
                tmp[i].u = ld_cp64(&hin[(size_t)(rb * 32 + r) * 512 + cc]);
            }
            asm volatile("s_waitcnt vmcnt(0)" ::: "memory");
            __builtin_amdgcn_sched_barrier(0);
            #pragma unroll
            for (int i = 0; i < 16; i++) {
                int L = i * 256 + tid;
                int r = L >> 7, cc = (L & 127) * 4;
                *(us4*)&As[r][cc] = tmp[i].v;
            }
            __syncthreads();

            f32x4 acc[4] = {};
            #pragma unroll
            for (int kk = 0; kk < 16; kk++) {
                short8 a = *(const short8*)&As[hi * 16 + lr][kk * 32 + lg * 8];
                acc[0] = __builtin_amdgcn_mfma_f32_16x16x32_bf16(a, bq[0][kk], acc[0], 0, 0, 0);
                acc[1] = __builtin_amdgcn_mfma_f32_16x16x32_bf16(a, bq[1][kk], acc[1], 0, 0, 0);
                acc[2] = __builtin_amdgcn_mfma_f32_16x16x32_bf16(a, bq[2][kk], acc[2], 0, 0, 0);
                acc[3] = __builtin_amdgcn_mfma_f32_16x16x32_bf16(a, bq[3][kk], acc[3], 0, 0, 0);
            }

            // lane-local epilogue; h + HnewC stores all sc0sc1, BEFORE the drain
            #pragma unroll
            for (int i = 0; i < 4; i++) {
                int act = (t < edec[i]);
                float iv = sigm(acc[0][i] + xq[0][i]);
                float fv = sigm(acc[1][i] + xq[1][i]);
                float gv = tanhf(acc[2][i] + xq[2][i]);
                float ov = sigm(acc[3][i] + xq[3][i]);
                float cn = fv * creg[i] + iv * gv;
                float hn_f = ov * tanhf(cn);
                if (act) {
                    creg[i] = cn;
                    hreg[i] = f2bf(hn_f);
                }
                st_cp16(&hout[(size_t)rowg[i] * 512 + col], (unsigned)hreg[i]);
                if (act)
                    st_cp16(&HnewC[(size_t)(offt + rowg[i]) * 512 + col], (unsigned)hreg[i]);
            }

            // drain all sc0sc1 stores, then post this step's completion
            asm volatile("s_waitcnt vmcnt(0)" ::: "memory");
            __syncthreads();
            if (tid == 0) atomicAdd(cnt, 1u);
        }
    } else {
        // ======================= fc GEMM consumer =======================
        u16 (*As)[40] = (u16(*)[40])smem;               // 10240 B
        u16 (*Bs)[40] = (u16(*)[40])(smem + 10240);     // 10240 B
        const int f = wg - NLSTM;
        const int w = tid >> 6, l = tid & 63;
        const int wr = (w >> 1) * 64, wc = (w & 1) * 64;
        const int lr = l & 15, lg = l >> 4;

        int nrC = offs[49];
        int nrt = (nrC + 127) >> 7;
        int njobs = nrt * 79;

        for (int j = f; j < njobs; j += NFC) {
            int rt = j / 79, cn = j - rt * 79;
            int lastrow = min(rt * 128 + 127, nrC - 1);
            int tmax = rowmap[lastrow] >> 7;
            unsigned tgt = 16u * (unsigned)(tmax + 1);
            if (tid < 4) {
                const unsigned* cp = slots + tid * 32;
                while (ld_cp32_wait(cp) < tgt) __builtin_amdgcn_s_sleep(1);
            }
            __syncthreads();

            f32x4 acc[4][4] = {};
            for (int k0 = 0; k0 < 512; k0 += 32) {
                __syncthreads();
                short8 av[2], bv[2];
                #pragma unroll
                for (int i = 0; i < 2; i++) {
                    int L = tid * 8 + i * 2048;
                    int r = L >> 5, c = L & 31;
                    int gr = min(rt * 128 + r, nrC - 1);
                    av[i] = ld_cp128(&HnewC[(size_t)gr * 512 + k0 + c]);
                }
                #pragma unroll
                for (int i = 0; i < 2; i++) {
                    int L = tid * 8 + i * 2048;
                    int r = L >> 5, c = L & 31;
                    int gn = cn * 128 + r;
                    short8 z = {};
                    bv[i] = (gn < NV) ? *(const short8*)&fcWB[(size_t)gn * 512 + k0 + c] : z;
                }
                asm volatile("s_waitcnt vmcnt(0)" ::: "memory");
                __builtin_amdgcn_sched_barrier(0);
                #pragma unroll
                for (int i = 0; i < 2; i++) {
                    int L = tid * 8 + i * 2048;
                    int r = L >> 5, c = L & 31;
                    short8 a = av[i];
                    if (rt * 128 + r >= nrC) { short8 z = {}; a = z; }
                    *(short8*)&As[r][c] = a;
                    *(short8*)&Bs[r][c] = bv[i];
                }
                __syncthreads();
                short8 af[4], bfr[4];
                #pragma unroll
                for (int m = 0; m < 4; m++) af[m] = *(const short8*)&As[wr + m * 16 + lr][lg * 8];
                #pragma unroll
                for (int n = 0; n < 4; n++) bfr[n] = *(const short8*)&Bs[wc + n * 16 + lr][lg * 8];
                #pragma unroll
                for (int m = 0; m < 4; m++)
                    #pragma unroll
                    for (int n = 0; n < 4; n++)
                        acc[m][n] = __builtin_amdgcn_mfma_f32_16x16x32_bf16(af[m], bfr[n], acc[m][n], 0, 0, 0);
            }

            #pragma unroll
            for (int m = 0; m < 4; m++) {
                #pragma unroll
                for (int n = 0; n < 4; n++) {
                    #pragma unroll
                    for (int i = 0; i < 4; i++) {
                        int row = rt * 128 + wr + m * 16 + lg * 4 + i;
                        int col = cn * 128 + wc + n * 16 + lr;
                        if (row < nrC && col < NV) {
                            int map = rowmap[row];
                            int b = map & 127, tt = map >> 7;
                            out[(size_t)b * 490000 + (size_t)tt * 10000 + col] =
                                acc[m][n][i] + fcb[col];
                        }
                    }
                }
            }
        }
    }
}

extern "C" void kernel_launch(void* const* d_in, const int* in_sizes, int n_in,
                              void* d_out, int out_size, void* d_ws, size_t ws_size,
                              hipStream_t stream) {
    const float* enc      = (const float*)d_in[0];
    const int*   captions = (const int*)d_in[1];
    const int*   caplens  = (const int*)d_in[2];
    const float* embW     = (const float*)d_in[3];
    const float* Wih      = (const float*)d_in[4];
    const float* Whh      = (const float*)d_in[5];
    const float* bih      = (const float*)d_in[6];
    const float* bhh      = (const float*)d_in[7];
    const float* fcW      = (const float*)d_in[8];
    const float* fcb      = (const float*)d_in[9];
    const float* ihW      = (const float*)d_in[10];
    const float* ihb      = (const float*)d_in[11];
    const float* icW      = (const float*)d_in[12];
    const float* icb      = (const float*)d_in[13];
    float* out = (float*)d_out;

    char* ws = (char*)d_ws;
    u16*   WihB = (u16*)(ws + 0);
    u16*   WhhB = (u16*)(ws + 2097152);
    u16*   fcWB = (u16*)(ws + 4194304);
    u16*   WhcB = (u16*)(ws + 14434304);
    u16*   encB = (u16*)(ws + 18628608);
    u16*   Xemb = (u16*)(ws + 19152896);
    float* X    = (float*)(ws + 25575424);
    u16*   HnewC= (u16*)(ws + 76955648);
    u16*   hb0  = (u16*)(ws + 83378176);
    u16*   hb1  = (u16*)(ws + 83509248);
    float* cf   = (float*)(ws + 83640320);
    int*   sidx = (int*)(ws + 83902464);
    int*   decl = (int*)(ws + 83902976);
    int*   capsS= (int*)(ws + 83903488);
    float* bsum = (float*)(ws + 83929088);
    unsigned* slots = (unsigned*)(ws + 83937280);   // 4 counters at 32-int stride
    int*   offs  = (int*)(ws + 83938304);           // 50 ints; offs[49] = nrowsC
    int*   rowmap= (int*)(ws + 83938560);           // 6272 ints

    k_sort<<<1, 128, 0, stream>>>(caplens, captions, bih, bhh, sidx, decl, capsS, bsum,
                                  out + 62720000, slots, offs, rowmap);
    k_zero<<<6272, 256, 0, stream>>>(decl, out);
    k_cvt<<<9096, 256, 0, stream>>>(Wih, Whh, fcW, ihW, icW, WihB, WhhB, fcWB, WhcB);
    k_gather<<<3392, 256, 0, stream>>>(enc, embW, sidx, capsS, encB, Xemb);
    // h0 | c0 : (128 x 1024) = encB (128x2048) @ WhcB^T
    gemm128<1><<<8, 256, 0, stream>>>(encB, 2048, WhcB, 2048, 1024, 2048, 1, 8,
                                      ihb, icb, nullptr, hb0, cf);
    // X = Xemb (6272x512) @ WihB^T (2048x512) + (b_ih+b_hh)
    gemm128<0><<<784, 256, 0, stream>>>(Xemb, 512, WihB, 512, 2048, 512, 49, 16,
                                        bsum, nullptr, X, nullptr, nullptr);
    // fused: 49 LSTM steps (64 WGs) + overlapped fc GEMM (192 WGs)
    lstm_fc<<<NLSTM + NFC, 256, SMEM_BYTES, stream>>>(
        WhhB, X, hb0, hb1, cf, HnewC, decl, slots, offs, rowmap, fcWB, fcb, out);
}

// Round 10
// 450.421 us; speedup vs baseline: 1.4776x; 1.0489x over previous
//
#include <hip/hip_runtime.h>
#include <hip/hip_bf16.h>
#include <math.h>

typedef __attribute__((ext_vector_type(8))) short short8;
typedef __attribute__((ext_vector_type(4))) float f32x4;
typedef __attribute__((ext_vector_type(4))) unsigned short us4;
typedef unsigned short u16;
typedef unsigned long long u64;

#define TM 49
#define NV 10000
#define NLSTM 64
#define NFC 192
#define SMEM_BYTES 86016

union U64c { us4 v; u64 u; };

__device__ __forceinline__ u16 f2bf(float f) {
    union { float f; unsigned u; } v; v.f = f;
    unsigned r = v.u + 0x7fffu + ((v.u >> 16) & 1u);
    return (u16)(r >> 16);
}
__device__ __forceinline__ float sigm(float x) { return 1.0f / (1.0f + expf(-x)); }

// coherence-point access helpers (sc0 sc1 = bypass L1+L2, device coherence point)
__device__ __forceinline__ u64 ld_cp64(const u16* p) {
    u64 r;
    asm volatile("global_load_dwordx2 %0, %1, off sc0 sc1" : "=v"(r) : "v"(p));
    return r;   // caller must s_waitcnt before use
}
__device__ __forceinline__ short8 ld_cp128(const u16* p) {
    short8 r;
    asm volatile("global_load_dwordx4 %0, %1, off sc0 sc1" : "=v"(r) : "v"(p));
    return r;   // caller must s_waitcnt before use
}
__device__ __forceinline__ unsigned ld_cp32_nw(const unsigned* p) {
    unsigned r;
    asm volatile("global_load_dword %0, %1, off sc0 sc1" : "=v"(r) : "v"(p));
    return r;   // caller must s_waitcnt before use
}
__device__ __forceinline__ void st_cp16(u16* p, unsigned v) {
    asm volatile("global_store_short %0, %1, off sc0 sc1" :: "v"(p), "v"(v) : "memory");
}
__device__ __forceinline__ void st_cp32f(float* p, float v) {
    asm volatile("global_store_dword %0, %1, off sc0 sc1" :: "v"(p), "v"(v) : "memory");
}
__device__ __forceinline__ unsigned ld_cp32_wait(const unsigned* p) {
    unsigned r;
    asm volatile("global_load_dword %0, %1, off sc0 sc1\n\ts_waitcnt vmcnt(0)"
                 : "=v"(r) : "v"(p) : "memory");
    return r;
}
__device__ __forceinline__ u16 ld_cp16_wait(const u16* p) {
    unsigned r;
    asm volatile("global_load_ushort %0, %1, off sc0 sc1\n\ts_waitcnt vmcnt(0)"
                 : "=v"(r) : "v"(p) : "memory");
    return (u16)r;
}

// ---------------- sort + metadata + compaction tables + small outputs ----------------
__global__ __launch_bounds__(128) void k_sort(
    const int* __restrict__ caplens, const int* __restrict__ captions,
    const float* __restrict__ bih, const float* __restrict__ bhh,
    int* __restrict__ sidx, int* __restrict__ decl, int* __restrict__ capsS,
    float* __restrict__ bsum, float* __restrict__ out_tail,
    unsigned* __restrict__ slots, int* __restrict__ offs, int* __restrict__ rowmap,
    int* __restrict__ maskmap)
{
    __shared__ int s_cl[128];
    __shared__ int s_si[128];
    __shared__ int s_dl[128];
    __shared__ int s_n[49];
    __shared__ int s_off[50];
    __shared__ int s_moff[128];
    int tid = threadIdx.x;
    for (int k = tid; k < 256; k += 128)   // reset counters (h groups + pre)
        __hip_atomic_store(&slots[k], 0u, __ATOMIC_RELAXED, __HIP_MEMORY_SCOPE_AGENT);
    int my = caplens[tid];
    s_cl[tid] = my;
    __syncthreads();
    int r = 0;
    for (int j = 0; j < 128; j++) {
        int cj = s_cl[j];
        if (cj > my || (cj == my && j < tid)) r++;
    }
    s_si[r] = tid;   // stable descending argsort
    __syncthreads();
    int src = s_si[tid];
    sidx[tid] = src;
    int dl = s_cl[src] - 1;
    decl[tid] = dl;
    s_dl[tid] = dl;
    out_tail[6400 + tid] = (float)dl;
    out_tail[6528 + tid] = (float)src;
    for (int t = 0; t < 50; t++) {
        int tok = captions[src * 50 + t];
        capsS[tid * 50 + t] = tok;
        out_tail[tid * 50 + t] = (float)tok;
    }
    for (int k = tid; k < 2048; k += 128) bsum[k] = bih[k] + bhh[k];
    __syncthreads();
    if (tid < 49) {
        int c = 0;
        for (int b = 0; b < 128; b++) c += (s_dl[b] > tid);
        s_n[tid] = c;
    }
    __syncthreads();
    if (tid == 0) {
        int a = 0;
        for (int t = 0; t < 49; t++) { s_off[t] = a; a += s_n[t]; }
        s_off[49] = a;   // total compacted rows
        int m = 0;
        for (int b = 0; b < 128; b++) { s_moff[b] = m; m += 49 - s_dl[b]; }
    }
    __syncthreads();
    if (tid < 50) offs[tid] = s_off[tid];
    for (int t = 0; t < dl; t++) rowmap[s_off[t] + tid] = t * 128 + tid;
    int mo = s_moff[tid];
    for (int t = dl; t < 49; t++) maskmap[mo + (t - dl)] = tid * 49 + t;
}

// ---------------- weight fp32 -> bf16 conversion ----------------
__global__ __launch_bounds__(256) void k_cvt(
    const float* __restrict__ Wih, const float* __restrict__ Whh,
    const float* __restrict__ fcW, const float* __restrict__ ihW,
    const float* __restrict__ icW,
    u16* __restrict__ WihB, u16* __restrict__ WhhB,
    u16* __restrict__ fcWB, u16* __restrict__ WhcB)
{
    int idx = blockIdx.x * 256 + threadIdx.x;  // float4 index, exact grid
    const float* src; u16* dst; int o;
    if (idx < 262144)        { src = Wih; dst = WihB; o = idx; }
    else if (idx < 524288)   { src = Whh; dst = WhhB; o = idx - 262144; }
    else if (idx < 1804288)  { src = fcW; dst = fcWB; o = idx - 524288; }
    else if (idx < 2066432)  { src = ihW; dst = WhcB; o = idx - 1804288; }
    else                     { src = icW; dst = WhcB + 1048576; o = idx - 2066432; }
    f32x4 v = *(const f32x4*)&src[(size_t)o * 4];
    us4 b = { f2bf(v.x), f2bf(v.y), f2bf(v.z), f2bf(v.w) };
    *(us4*)&dst[(size_t)o * 4] = b;
}

// ---------------- gathers: sorted enc -> bf16, embedding -> bf16 ----------------
__global__ __launch_bounds__(256) void k_gather(
    const float* __restrict__ enc, const float* __restrict__ embW,
    const int* __restrict__ sidx, const int* __restrict__ capsS,
    u16* __restrict__ encB, u16* __restrict__ Xemb)
{
    int idx = blockIdx.x * 256 + threadIdx.x;
    if (idx < 65536) {
        int b = idx >> 9, k4 = idx & 511;
        f32x4 v = *(const f32x4*)&enc[(size_t)sidx[b] * 2048 + k4 * 4];
        us4 o = { f2bf(v.x), f2bf(v.y), f2bf(v.z), f2bf(v.w) };
        *(us4*)&encB[(size_t)b * 2048 + k4 * 4] = o;
    } else {
        int j = idx - 65536;              // < 802816
        int row = j >> 7, k4 = j & 127;   // row = t*128 + b
        int t = row >> 7, b = row & 127;
        int tok = capsS[b * 50 + t];
        f32x4 v = *(const f32x4*)&embW[(size_t)tok * 512 + k4 * 4];
        us4 o = { f2bf(v.x), f2bf(v.y), f2bf(v.z), f2bf(v.w) };
        *(us4*)&Xemb[(size_t)row * 512 + k4 * 4] = o;
    }
}

// ---- shared 128x128 tile GEMM body (plain loads, full 128 valid rows both sides) ----
__device__ __forceinline__ void tile_gemm_plain(
    const u16* __restrict__ A, int lda, const u16* __restrict__ B, int ldb,
    int K, int tid, u16 (*As)[40], u16 (*Bs)[40], f32x4 acc[4][4])
{
    const int w = tid >> 6, l = tid & 63;
    const int wr = (w >> 1) * 64, wc = (w & 1) * 64;
    const int lr = l & 15, lg = l >> 4;
    for (int k0 = 0; k0 < K; k0 += 32) {
        __syncthreads();
        #pragma unroll
        for (int i = 0; i < 2; i++) {
            int L = tid * 8 + i * 2048;
            int r = L >> 5, c = L & 31;
            *(short8*)&As[r][c] = *(const short8*)&A[(size_t)r * lda + k0 + c];
            *(short8*)&Bs[r][c] = *(const short8*)&B[(size_t)r * ldb + k0 + c];
        }
        __syncthreads();
        short8 af[4], bfr[4];
        #pragma unroll
        for (int m = 0; m < 4; m++) af[m] = *(const short8*)&As[wr + m * 16 + lr][lg * 8];
        #pragma unroll
        for (int n = 0; n < 4; n++) bfr[n] = *(const short8*)&Bs[wc + n * 16 + lr][lg * 8];
        #pragma unroll
        for (int m = 0; m < 4; m++)
            #pragma unroll
            for (int n = 0; n < 4; n++)
                acc[m][n] = __builtin_amdgcn_mfma_f32_16x16x32_bf16(af[m], bfr[n], acc[m][n], 0, 0, 0);
    }
}

// ---------------- fused persistent kernel ----------------
// blocks 0..63:   LSTM recurrence producers (gate at start on pre==792).
// blocks 64..255: consumers. Job list per WG (j = f; j += NFC):
//   j<8:        h0/c0 tile (encB @ WhcB^T), sc0sc1 out, post pre
//   j<792:      X tile (Xemb @ WihB^T + bsum), sc0sc1 out, post pre
//   j<792+nz:   zero-fill 2 masked out-rows (replaces k_zero, no gate)
//   else:       fc tile (HnewC @ fcWB^T + fcb), gated on producer counters
__global__ __launch_bounds__(256, 1) void lstm_fc(
    const u16* __restrict__ Whh, float* __restrict__ X,
    u16* __restrict__ hb0, u16* __restrict__ hb1,
    float* __restrict__ cf, u16* __restrict__ HnewC,
    const int* __restrict__ decl, unsigned* __restrict__ slots,
    const int* __restrict__ offs, const int* __restrict__ rowmap,
    const int* __restrict__ maskmap,
    const u16* __restrict__ fcWB, const float* __restrict__ fcb,
    const u16* __restrict__ encB, const u16* __restrict__ WhcB,
    const u16* __restrict__ WihB, const u16* __restrict__ Xemb,
    const float* __restrict__ bsum,
    const float* __restrict__ ihb, const float* __restrict__ icb,
    float* __restrict__ out)
{
    extern __shared__ char smem[];
    const int tid = threadIdx.x;
    const int wg = blockIdx.x;
    unsigned* pre = slots + 128;

    if (wg < NLSTM) {
        // ======================= recurrence producer =======================
        u16 (*As)[520] = (u16(*)[520])smem;   // 32 x 520 u16 = 33280 B
        const int rb = wg >> 4, cb = wg & 15;
        const int w = tid >> 6, l = tid & 63;
        const int hi = w >> 1, lo = w & 1;
        const int lr = l & 15, lg = l >> 4;
        unsigned* cnt = slots + rb * 32;

        const int col = cb * 32 + lo * 16 + lr;
        int rowg[4];
        #pragma unroll
        for (int i = 0; i < 4; i++) rowg[i] = rb * 32 + hi * 16 + lg * 4 + i;

        // Whh fragments (plain loads; written by earlier kernel)
        short8 bq[4][16];
        #pragma unroll
        for (int q = 0; q < 4; q++) {
            const u16* base = &Whh[(size_t)(q * 512 + cb * 32 + lo * 16 + lr) * 512 + lg * 8];
            #pragma unroll
            for (int kk = 0; kk < 16; kk++)
                bq[q][kk] = *(const short8*)&base[kk * 32];
        }
        #pragma unroll
        for (int q = 0; q < 4; q++)
            #pragma unroll
            for (int kk = 0; kk < 16; kk++)
                asm volatile("" : "+v"(bq[q][kk]));   // pin: no remat of weight loads

        // gate: all h0/c0 + X pre-jobs done
        if (tid == 0) {
            while (ld_cp32_wait(pre) < 792u) __builtin_amdgcn_s_sleep(2);
        }
        __syncthreads();

        int edec[4];
        f32x4 creg;
        us4 hreg;
        #pragma unroll
        for (int i = 0; i < 4; i++) {
            edec[i] = decl[rowg[i]];
            union { unsigned u; float f; } cv;
            cv.u = ld_cp32_wait((const unsigned*)&cf[(size_t)rowg[i] * 512 + col]);
            creg[i] = cv.f;
            hreg[i] = ld_cp16_wait(&hb0[(size_t)rowg[i] * 512 + col]);
        }

        for (int t = 0; t < TM; t++) {
            const u16* hin = (t & 1) ? hb1 : hb0;
            u16* hout = (t & 1) ? hb0 : hb1;

            // X[t] gate addends via pipelined sc0sc1 loads (drained by stage drain)
            unsigned xqu[16];
            #pragma unroll
            for (int q = 0; q < 4; q++)
                #pragma unroll
                for (int i = 0; i < 4; i++)
                    xqu[q * 4 + i] = ld_cp32_nw((const unsigned*)
                        &X[(size_t)t * 262144 + (size_t)rowg[i] * 2048 + q * 512 + col]);
            int offt = offs[t];

            if (t > 0) {
                if (tid == 0) {
                    unsigned tgt = 16u * (unsigned)t;
                    while (ld_cp32_wait(cnt) < tgt) __builtin_amdgcn_s_sleep(1);
                }
                __syncthreads();
            }

            // stage 32x512 h tile: 16 pipelined sc0sc1 loads, one drain, LDS writes
            U64c tmp[16];
            #pragma unroll
            for (int i = 0; i < 16; i++) {
                int L = i * 256 + tid;          // u64 index; 4096 total
                int r = L >> 7, cc = (L & 127) * 4;
                tmp[i].u = ld_cp64(&hin[(size_t)(rb * 32 + r) * 512 + cc]);
            }
            asm volatile("s_waitcnt vmcnt(0)" ::: "memory");
            __builtin_amdgcn_sched_barrier(0);
            #pragma unroll
            for (int i = 0; i < 16; i++) {
                int L = i * 256 + tid;
                int r = L >> 7, cc = (L & 127) * 4;
                *(us4*)&As[r][cc] = tmp[i].v;
            }
            __syncthreads();

            f32x4 acc[4] = {};
            #pragma unroll
            for (int kk = 0; kk < 16; kk++) {
                short8 a = *(const short8*)&As[hi * 16 + lr][kk * 32 + lg * 8];
                acc[0] = __builtin_amdgcn_mfma_f32_16x16x32_bf16(a, bq[0][kk], acc[0], 0, 0, 0);
                acc[1] = __builtin_amdgcn_mfma_f32_16x16x32_bf16(a, bq[1][kk], acc[1], 0, 0, 0);
                acc[2] = __builtin_amdgcn_mfma_f32_16x16x32_bf16(a, bq[2][kk], acc[2], 0, 0, 0);
                acc[3] = __builtin_amdgcn_mfma_f32_16x16x32_bf16(a, bq[3][kk], acc[3], 0, 0, 0);
            }

            // lane-local epilogue; h + HnewC stores sc0sc1, BEFORE the drain
            #pragma unroll
            for (int i = 0; i < 4; i++) {
                int act = (t < edec[i]);
                union { unsigned u; float f; } x0, x1, x2, x3;
                x0.u = xqu[0 * 4 + i]; x1.u = xqu[1 * 4 + i];
                x2.u = xqu[2 * 4 + i]; x3.u = xqu[3 * 4 + i];
                float iv = sigm(acc[0][i] + x0.f);
                float fv = sigm(acc[1][i] + x1.f);
                float gv = tanhf(acc[2][i] + x2.f);
                float ov = sigm(acc[3][i] + x3.f);
                float cn = fv * creg[i] + iv * gv;
                float hn_f = ov * tanhf(cn);
                if (act) {
                    creg[i] = cn;
                    hreg[i] = f2bf(hn_f);
                }
                st_cp16(&hout[(size_t)rowg[i] * 512 + col], (unsigned)hreg[i]);
                if (act)
                    st_cp16(&HnewC[(size_t)(offt + rowg[i]) * 512 + col], (unsigned)hreg[i]);
            }

            // drain all sc0sc1 stores, then post this step's completion
            asm volatile("s_waitcnt vmcnt(0)" ::: "memory");
            __syncthreads();
            if (tid == 0) atomicAdd(cnt, 1u);
        }
    } else {
        // ======================= consumer =======================
        u16 (*As)[40] = (u16(*)[40])smem;               // 10240 B
        u16 (*Bs)[40] = (u16(*)[40])(smem + 10240);     // 10240 B
        const int f = wg - NLSTM;
        const int w = tid >> 6, l = tid & 63;
        const int wr = (w >> 1) * 64, wc = (w & 1) * 64;
        const int lr = l & 15, lg = l >> 4;

        int nrC = offs[49];
        int nzero = 6272 - nrC;
        int nzjobs = (nzero + 1) >> 1;
        int nrt = (nrC + 127) >> 7;
        int total = 792 + nzjobs + nrt * 79;

        for (int j = f; j < total; j += NFC) {
            if (j < 8) {
                // ---- h0 | c0 tile: cols j*128..j*128+127 of encB @ WhcB^T ----
                f32x4 acc[4][4] = {};
                tile_gemm_plain(encB, 2048, WhcB + (size_t)j * 128 * 2048, 2048,
                                2048, tid, As, Bs, acc);
                #pragma unroll
                for (int m = 0; m < 4; m++)
                    #pragma unroll
                    for (int n = 0; n < 4; n++)
                        #pragma unroll
                        for (int i = 0; i < 4; i++) {
                            int row = wr + m * 16 + lg * 4 + i;
                            int colg = j * 128 + wc + n * 16 + lr;
                            float v = acc[m][n][i];
                            if (colg < 512)
                                st_cp16(&hb0[(size_t)row * 512 + colg],
                                        (unsigned)f2bf(v + ihb[colg]));
                            else
                                st_cp32f(&cf[(size_t)row * 512 + colg - 512],
                                         v + icb[colg - 512]);
                        }
                asm volatile("s_waitcnt vmcnt(0)" ::: "memory");
                __syncthreads();
                if (tid == 0) atomicAdd(pre, 1u);
            } else if (j < 792) {
                // ---- X tile: X[tt][:, cbx*128..] = Xemb[tt] @ WihB^T + bsum ----
                int xj = j - 8, tt = xj >> 4, cbx = xj & 15;
                f32x4 acc[4][4] = {};
                tile_gemm_plain(Xemb + (size_t)tt * 128 * 512, 512,
                                WihB + (size_t)cbx * 128 * 512, 512,
                                512, tid, As, Bs, acc);
                #pragma unroll
                for (int m = 0; m < 4; m++)
                    #pragma unroll
                    for (int n = 0; n < 4; n++)
                        #pragma unroll
                        for (int i = 0; i < 4; i++) {
                            int row = wr + m * 16 + lg * 4 + i;
                            int colg = cbx * 128 + wc + n * 16 + lr;
                            st_cp32f(&X[(size_t)tt * 262144 + (size_t)row * 2048 + colg],
                                     acc[m][n][i] + bsum[colg]);
                        }
                asm volatile("s_waitcnt vmcnt(0)" ::: "memory");
                __syncthreads();
                if (tid == 0) atomicAdd(pre, 1u);
            } else if (j < 792 + nzjobs) {
                // ---- zero-fill two masked out-rows ----
                int z = (j - 792) * 2;
                #pragma unroll
                for (int rr = 0; rr < 2; rr++) {
                    if (z + rr < nzero) {
                        float* dst = out + (size_t)maskmap[z + rr] * 10000;
                        f32x4 zv = {};
                        for (int i = tid; i < 2500; i += 256) *(f32x4*)&dst[i * 4] = zv;
                    }
                }
            } else {
                // ---- fc tile on compacted rows, gated on producer progress ----
                int jf = j - 792 - nzjobs;
                int rt = jf / 79, cn = jf - rt * 79;
                int lastrow = min(rt * 128 + 127, nrC - 1);
                int tmax = rowmap[lastrow] >> 7;
                unsigned tgt = 16u * (unsigned)(tmax + 1);
                if (tid < 4) {
                    const unsigned* cp = slots + tid * 32;
                    while (ld_cp32_wait(cp) < tgt) __builtin_amdgcn_s_sleep(1);
                }
                __syncthreads();

                f32x4 acc[4][4] = {};
                for (int k0 = 0; k0 < 512; k0 += 32) {
                    __syncthreads();
                    short8 av[2], bv[2];
                    #pragma unroll
                    for (int i = 0; i < 2; i++) {
                        int L = tid * 8 + i * 2048;
                        int r = L >> 5, c = L & 31;
                        int gr = min(rt * 128 + r, nrC - 1);
                        av[i] = ld_cp128(&HnewC[(size_t)gr * 512 + k0 + c]);
                    }
                    #pragma unroll
                    for (int i = 0; i < 2; i++) {
                        int L = tid * 8 + i * 2048;
                        int r = L >> 5, c = L & 31;
                        int gn = cn * 128 + r;
                        short8 z = {};
                        bv[i] = (gn < NV) ? *(const short8*)&fcWB[(size_t)gn * 512 + k0 + c] : z;
                    }
                    asm volatile("s_waitcnt vmcnt(0)" ::: "memory");
                    __builtin_amdgcn_sched_barrier(0);
                    #pragma unroll
                    for (int i = 0; i < 2; i++) {
                        int L = tid * 8 + i * 2048;
                        int r = L >> 5, c = L & 31;
                        short8 a = av[i];
                        if (rt * 128 + r >= nrC) { short8 z = {}; a = z; }
                        *(short8*)&As[r][c] = a;
                        *(short8*)&Bs[r][c] = bv[i];
                    }
                    __syncthreads();
                    short8 af[4], bfr[4];
                    #pragma unroll
                    for (int m = 0; m < 4; m++) af[m] = *(const short8*)&As[wr + m * 16 + lr][lg * 8];
                    #pragma unroll
                    for (int n = 0; n < 4; n++) bfr[n] = *(const short8*)&Bs[wc + n * 16 + lr][lg * 8];
                    #pragma unroll
                    for (int m = 0; m < 4; m++)
                        #pragma unroll
                        for (int n = 0; n < 4; n++)
                            acc[m][n] = __builtin_amdgcn_mfma_f32_16x16x32_bf16(af[m], bfr[n], acc[m][n], 0, 0, 0);
                }

                #pragma unroll
                for (int m = 0; m < 4; m++)
                    #pragma unroll
                    for (int n = 0; n < 4; n++)
                        #pragma unroll
                        for (int i = 0; i < 4; i++) {
                            int row = rt * 128 + wr + m * 16 + lg * 4 + i;
                            int colg = cn * 128 + wc + n * 16 + lr;
                            if (row < nrC && colg < NV) {
                                int map = rowmap[row];
                                int b = map & 127, tt = map >> 7;
                                out[(size_t)(b * 49 + tt) * 10000 + colg] =
                                    acc[m][n][i] + fcb[colg];
                            }
                        }
            }
        }
    }
}

extern "C" void kernel_launch(void* const* d_in, const int* in_sizes, int n_in,
                              void* d_out, int out_size, void* d_ws, size_t ws_size,
                              hipStream_t stream) {
    const float* enc      = (const float*)d_in[0];
    const int*   captions = (const int*)d_in[1];
    const int*   caplens  = (const int*)d_in[2];
    const float* embW     = (const float*)d_in[3];
    const float* Wih      = (const float*)d_in[4];
    const float* Whh      = (const float*)d_in[5];
    const float* bih      = (const float*)d_in[6];
    const float* bhh      = (const float*)d_in[7];
    const float* fcW      = (const float*)d_in[8];
    const float* fcb      = (const float*)d_in[9];
    const float* ihW      = (const float*)d_in[10];
    const float* ihb      = (const float*)d_in[11];
    const float* icW      = (const float*)d_in[12];
    const float* icb      = (const float*)d_in[13];
    float* out = (float*)d_out;

    char* ws = (char*)d_ws;
    u16*   WihB = (u16*)(ws + 0);
    u16*   WhhB = (u16*)(ws + 2097152);
    u16*   fcWB = (u16*)(ws + 4194304);
    u16*   WhcB = (u16*)(ws + 14434304);
    u16*   encB = (u16*)(ws + 18628608);
    u16*   Xemb = (u16*)(ws + 19152896);
    float* X    = (float*)(ws + 25575424);
    u16*   HnewC= (u16*)(ws + 76955648);
    u16*   hb0  = (u16*)(ws + 83378176);
    u16*   hb1  = (u16*)(ws + 83509248);
    float* cf   = (float*)(ws + 83640320);
    int*   sidx = (int*)(ws + 83902464);
    int*   decl = (int*)(ws + 83902976);
    int*   capsS= (int*)(ws + 83903488);
    float* bsum = (float*)(ws + 83929088);
    unsigned* slots = (unsigned*)(ws + 83937280);   // h counters @ rb*32, pre @ 128
    int*   offs   = (int*)(ws + 83938304);          // 50 ints; offs[49] = nrowsC
    int*   rowmap = (int*)(ws + 83938560);          // 6272 ints
    int*   maskmap= (int*)(ws + 83963648);          // 6272 ints

    k_sort<<<1, 128, 0, stream>>>(caplens, captions, bih, bhh, sidx, decl, capsS, bsum,
                                  out + 62720000, slots, offs, rowmap, maskmap);
    k_cvt<<<9096, 256, 0, stream>>>(Wih, Whh, fcW, ihW, icW, WihB, WhhB, fcWB, WhcB);
    k_gather<<<3392, 256, 0, stream>>>(enc, embW, sidx, capsS, encB, Xemb);
    // fused: h0/c0 + X precompute + zero-fill + 49 LSTM steps + fc GEMM
    lstm_fc<<<NLSTM + NFC, 256, SMEM_BYTES, stream>>>(
        WhhB, X, hb0, hb1, cf, HnewC, decl, slots, offs, rowmap, maskmap,
        fcWB, fcb, encB, WhcB, WihB, Xemb, bsum, ihb, icb, out);
}

// Round 11
// 432.426 us; speedup vs baseline: 1.5391x; 1.0416x over previous
//
#include <hip/hip_runtime.h>
#include <hip/hip_bf16.h>
#include <math.h>

typedef __attribute__((ext_vector_type(8))) short short8;
typedef __attribute__((ext_vector_type(4))) float f32x4;
typedef __attribute__((ext_vector_type(4))) unsigned short us4;
typedef unsigned short u16;
typedef unsigned long long u64;

#define TM 49
#define NV 10000
#define NLSTM 64
#define NFC 192
#define SMEM_BYTES 86016

union U64c { us4 v; u64 u; };

__device__ __forceinline__ u16 f2bf(float f) {
    union { float f; unsigned u; } v; v.f = f;
    unsigned r = v.u + 0x7fffu + ((v.u >> 16) & 1u);
    return (u16)(r >> 16);
}
__device__ __forceinline__ float sigm(float x) { return 1.0f / (1.0f + expf(-x)); }

// coherence-point access helpers (sc0 sc1 = bypass L1+L2, device coherence point)
__device__ __forceinline__ u64 ld_cp64(const u16* p) {
    u64 r;
    asm volatile("global_load_dwordx2 %0, %1, off sc0 sc1" : "=v"(r) : "v"(p));
    return r;   // caller must s_waitcnt before use
}
__device__ __forceinline__ void st_cp16(u16* p, unsigned v) {
    asm volatile("global_store_short %0, %1, off sc0 sc1" :: "v"(p), "v"(v) : "memory");
}
__device__ __forceinline__ void st_cp32f(float* p, float v) {
    asm volatile("global_store_dword %0, %1, off sc0 sc1" :: "v"(p), "v"(v) : "memory");
}
__device__ __forceinline__ unsigned ld_cp32_wait(const unsigned* p) {
    unsigned r;
    asm volatile("global_load_dword %0, %1, off sc0 sc1\n\ts_waitcnt vmcnt(0)"
                 : "=v"(r) : "v"(p) : "memory");
    return r;
}

// ---------------- sort + metadata + compaction tables + small outputs ----------------
__global__ __launch_bounds__(128) void k_sort(
    const int* __restrict__ caplens, const int* __restrict__ captions,
    const float* __restrict__ bih, const float* __restrict__ bhh,
    int* __restrict__ sidx, int* __restrict__ decl, int* __restrict__ capsS,
    float* __restrict__ bsum, float* __restrict__ out_tail,
    unsigned* __restrict__ slots, unsigned* __restrict__ xcnt,
    int* __restrict__ offs, int* __restrict__ rowmap, int* __restrict__ maskmap)
{
    __shared__ int s_cl[128];
    __shared__ int s_si[128];
    __shared__ int s_dl[128];
    __shared__ int s_n[49];
    __shared__ int s_off[50];
    __shared__ int s_moff[128];
    int tid = threadIdx.x;
    for (int k = tid; k < 256; k += 128)    // reset h-group counters
        __hip_atomic_store(&slots[k], 0u, __ATOMIC_RELAXED, __HIP_MEMORY_SCOPE_AGENT);
    for (int k = tid; k < 1568; k += 128)   // reset per-t X counters
        __hip_atomic_store(&xcnt[k], 0u, __ATOMIC_RELAXED, __HIP_MEMORY_SCOPE_AGENT);
    int my = caplens[tid];
    s_cl[tid] = my;
    __syncthreads();
    int r = 0;
    for (int j = 0; j < 128; j++) {
        int cj = s_cl[j];
        if (cj > my || (cj == my && j < tid)) r++;
    }
    s_si[r] = tid;   // stable descending argsort
    __syncthreads();
    int src = s_si[tid];
    sidx[tid] = src;
    int dl = s_cl[src] - 1;
    decl[tid] = dl;
    s_dl[tid] = dl;
    out_tail[6400 + tid] = (float)dl;
    out_tail[6528 + tid] = (float)src;
    for (int t = 0; t < 50; t++) {
        int tok = captions[src * 50 + t];
        capsS[tid * 50 + t] = tok;
        out_tail[tid * 50 + t] = (float)tok;
    }
    for (int k = tid; k < 2048; k += 128) bsum[k] = bih[k] + bhh[k];
    __syncthreads();
    if (tid < 49) {
        int c = 0;
        for (int b = 0; b < 128; b++) c += (s_dl[b] > tid);
        s_n[tid] = c;
    }
    __syncthreads();
    if (tid == 0) {
        int a = 0;
        for (int t = 0; t < 49; t++) { s_off[t] = a; a += s_n[t]; }
        s_off[49] = a;   // total compacted rows
        int m = 0;
        for (int b = 0; b < 128; b++) { s_moff[b] = m; m += 49 - s_dl[b]; }
    }
    __syncthreads();
    if (tid < 50) offs[tid] = s_off[tid];
    for (int t = 0; t < dl; t++) rowmap[s_off[t] + tid] = t * 128 + tid;
    int mo = s_moff[tid];
    for (int t = dl; t < 49; t++) maskmap[mo + (t - dl)] = tid * 49 + t;
}

// ---------------- weight fp32 -> bf16 conversion ----------------
__global__ __launch_bounds__(256) void k_cvt(
    const float* __restrict__ Wih, const float* __restrict__ Whh,
    const float* __restrict__ fcW, const float* __restrict__ ihW,
    const float* __restrict__ icW,
    u16* __restrict__ WihB, u16* __restrict__ WhhB,
    u16* __restrict__ fcWB, u16* __restrict__ WhcB)
{
    int idx = blockIdx.x * 256 + threadIdx.x;  // float4 index, exact grid
    const float* src; u16* dst; int o;
    if (idx < 262144)        { src = Wih; dst = WihB; o = idx; }
    else if (idx < 524288)   { src = Whh; dst = WhhB; o = idx - 262144; }
    else if (idx < 1804288)  { src = fcW; dst = fcWB; o = idx - 524288; }
    else if (idx < 2066432)  { src = ihW; dst = WhcB; o = idx - 1804288; }
    else                     { src = icW; dst = WhcB + 1048576; o = idx - 2066432; }
    f32x4 v = *(const f32x4*)&src[(size_t)o * 4];
    us4 b = { f2bf(v.x), f2bf(v.y), f2bf(v.z), f2bf(v.w) };
    *(us4*)&dst[(size_t)o * 4] = b;
}

// ---------------- gathers: sorted enc -> bf16, embedding -> bf16 ----------------
__global__ __launch_bounds__(256) void k_gather(
    const float* __restrict__ enc, const float* __restrict__ embW,
    const int* __restrict__ sidx, const int* __restrict__ capsS,
    u16* __restrict__ encB, u16* __restrict__ Xemb)
{
    int idx = blockIdx.x * 256 + threadIdx.x;
    if (idx < 65536) {
        int b = idx >> 9, k4 = idx & 511;
        f32x4 v = *(const f32x4*)&enc[(size_t)sidx[b] * 2048 + k4 * 4];
        us4 o = { f2bf(v.x), f2bf(v.y), f2bf(v.z), f2bf(v.w) };
        *(us4*)&encB[(size_t)b * 2048 + k4 * 4] = o;
    } else {
        int j = idx - 65536;              // < 802816
        int row = j >> 7, k4 = j & 127;   // row = t*128 + b
        int t = row >> 7, b = row & 127;
        int tok = capsS[b * 50 + t];
        f32x4 v = *(const f32x4*)&embW[(size_t)tok * 512 + k4 * 4];
        us4 o = { f2bf(v.x), f2bf(v.y), f2bf(v.z), f2bf(v.w) };
        *(us4*)&Xemb[(size_t)row * 512 + k4 * 4] = o;
    }
}

// ---- shared 128x128 tile GEMM body (plain loads, full 128 valid rows both sides) ----
__device__ __forceinline__ void tile_gemm_plain(
    const u16* __restrict__ A, int lda, const u16* __restrict__ B, int ldb,
    int K, int tid, u16 (*As)[40], u16 (*Bs)[40], f32x4 acc[4][4])
{
    const int w = tid >> 6, l = tid & 63;
    const int wr = (w >> 1) * 64, wc = (w & 1) * 64;
    const int lr = l & 15, lg = l >> 4;
    for (int k0 = 0; k0 < K; k0 += 32) {
        __syncthreads();
        #pragma unroll
        for (int i = 0; i < 2; i++) {
            int L = tid * 8 + i * 2048;
            int r = L >> 5, c = L & 31;
            *(short8*)&As[r][c] = *(const short8*)&A[(size_t)r * lda + k0 + c];
            *(short8*)&Bs[r][c] = *(const short8*)&B[(size_t)r * ldb + k0 + c];
        }
        __syncthreads();
        short8 af[4], bfr[4];
        #pragma unroll
        for (int m = 0; m < 4; m++) af[m] = *(const short8*)&As[wr + m * 16 + lr][lg * 8];
        #pragma unroll
        for (int n = 0; n < 4; n++) bfr[n] = *(const short8*)&Bs[wc + n * 16 + lr][lg * 8];
        #pragma unroll
        for (int m = 0; m < 4; m++)
            #pragma unroll
            for (int n = 0; n < 4; n++)
                acc[m][n] = __builtin_amdgcn_mfma_f32_16x16x32_bf16(af[m], bfr[n], acc[m][n], 0, 0, 0);
    }
}

// ---------------- fused persistent kernel ----------------
// blocks 0..63:   LSTM producers. Each computes its own h0/c0 patch (encB@WhcB^T,
//                 K=2048 in 4 LDS chunks), publishes h0 via the exchange (pseudo-step
//                 post), then 49 steps gated per-t on X availability (xcnt[t]==16)
//                 and on the group h-counter.
// blocks 64..255: consumers. Jobs: 784 X tiles (t-ascending, post xcnt[t]) ->
//                 zero-fill masked out rows -> fc tiles (plain L2-cached A reads,
//                 gated on producer counters).
__global__ __launch_bounds__(256, 1) void lstm_fc(
    const u16* __restrict__ Whh, float* __restrict__ X,
    u16* __restrict__ hb0, u16* __restrict__ hb1,
    u16* __restrict__ HnewC,
    const int* __restrict__ decl, unsigned* __restrict__ slots,
    unsigned* __restrict__ xcnt,
    const int* __restrict__ offs, const int* __restrict__ rowmap,
    const int* __restrict__ maskmap,
    const u16* __restrict__ fcWB, const float* __restrict__ fcb,
    const u16* __restrict__ encB, const u16* __restrict__ WhcB,
    const u16* __restrict__ WihB, const u16* __restrict__ Xemb,
    const float* __restrict__ bsum,
    const float* __restrict__ ihb, const float* __restrict__ icb,
    float* __restrict__ out)
{
    extern __shared__ char smem[];
    const int tid = threadIdx.x;
    const int wg = blockIdx.x;

    if (wg < NLSTM) {
        // ======================= recurrence producer =======================
        u16 (*As)[520] = (u16(*)[520])smem;              // 33280 B
        u16 (*Bsi)[520] = (u16(*)[520])(smem + 33280);   // 33280 B (init only)
        const int rb = wg >> 4, cb = wg & 15;
        const int w = tid >> 6, l = tid & 63;
        const int hi = w >> 1, lo = w & 1;
        const int lr = l & 15, lg = l >> 4;
        unsigned* cnt = slots + rb * 32;

        const int col = cb * 32 + lo * 16 + lr;
        int rowg[4];
        #pragma unroll
        for (int i = 0; i < 4; i++) rowg[i] = rb * 32 + hi * 16 + lg * 4 + i;

        // ---- init: h0/c0 for this WG's 32x32 patches (K=2048, 4 chunks) ----
        f32x4 acch = {}, accc = {};
        for (int kq = 0; kq < 4; kq++) {
            __syncthreads();
            #pragma unroll
            for (int i = 0; i < 8; i++) {
                int L = tid * 8 + i * 2048;
                int r = L >> 9, cc = L & 511;
                *(short8*)&As[r][cc] =
                    *(const short8*)&encB[(size_t)(rb * 32 + r) * 2048 + kq * 512 + cc];
                *(short8*)&Bsi[r][cc] =
                    *(const short8*)&WhcB[(size_t)(cb * 32 + r) * 2048 + kq * 512 + cc];
            }
            __syncthreads();
            #pragma unroll
            for (int kk = 0; kk < 16; kk++) {
                short8 a = *(const short8*)&As[hi * 16 + lr][kk * 32 + lg * 8];
                short8 b = *(const short8*)&Bsi[lo * 16 + lr][kk * 32 + lg * 8];
                acch = __builtin_amdgcn_mfma_f32_16x16x32_bf16(a, b, acch, 0, 0, 0);
            }
            __syncthreads();
            #pragma unroll
            for (int i = 0; i < 8; i++) {
                int L = tid * 8 + i * 2048;
                int r = L >> 9, cc = L & 511;
                *(short8*)&Bsi[r][cc] =
                    *(const short8*)&WhcB[(size_t)(512 + cb * 32 + r) * 2048 + kq * 512 + cc];
            }
            __syncthreads();
            #pragma unroll
            for (int kk = 0; kk < 16; kk++) {
                short8 a = *(const short8*)&As[hi * 16 + lr][kk * 32 + lg * 8];
                short8 b = *(const short8*)&Bsi[lo * 16 + lr][kk * 32 + lg * 8];
                accc = __builtin_amdgcn_mfma_f32_16x16x32_bf16(a, b, accc, 0, 0, 0);
            }
        }

        int edec[4];
        f32x4 creg;
        us4 hreg;
        #pragma unroll
        for (int i = 0; i < 4; i++) {
            edec[i] = decl[rowg[i]];
            creg[i] = accc[i] + icb[col];
            hreg[i] = f2bf(acch[i] + ihb[col]);
            st_cp16(&hb0[(size_t)rowg[i] * 512 + col], (unsigned)hreg[i]);
        }
        asm volatile("s_waitcnt vmcnt(0)" ::: "memory");
        __syncthreads();
        if (tid == 0) atomicAdd(cnt, 1u);   // init publish -> cnt reaches 16/group

        // ---- Whh fragments into registers (plain; L2/L3) ----
        short8 bq[4][16];
        #pragma unroll
        for (int q = 0; q < 4; q++) {
            const u16* base = &Whh[(size_t)(q * 512 + cb * 32 + lo * 16 + lr) * 512 + lg * 8];
            #pragma unroll
            for (int kk = 0; kk < 16; kk++)
                bq[q][kk] = *(const short8*)&base[kk * 32];
        }
        #pragma unroll
        for (int q = 0; q < 4; q++)
            #pragma unroll
            for (int kk = 0; kk < 16; kk++)
                asm volatile("" : "+v"(bq[q][kk]));   // pin: no remat of weight loads

        for (int t = 0; t < TM; t++) {
            const u16* hin = (t & 1) ? hb1 : hb0;
            u16* hout = (t & 1) ? hb0 : hb1;

            // gate on X[t] availability (16 tiles posted by consumers)
            if (tid == 0) {
                while (ld_cp32_wait(&xcnt[t * 32]) < 16u) __builtin_amdgcn_s_sleep(1);
            }
            __syncthreads();

            // X[t] gate addends: plain loads (writers used sc0sc1 -> first touch fresh)
            float xq[4][4];
            #pragma unroll
            for (int q = 0; q < 4; q++)
                #pragma unroll
                for (int i = 0; i < 4; i++)
                    xq[q][i] = X[(size_t)t * 262144 + (size_t)rowg[i] * 2048 + q * 512 + col];
            int offt = offs[t];

            // gate on h(t-1) complete within this row-group
            if (tid == 0) {
                unsigned tgt = 16u * (unsigned)(t + 1);
                while (ld_cp32_wait(cnt) < tgt) __builtin_amdgcn_s_sleep(1);
            }
            __syncthreads();

            // stage 32x512 h tile: 16 pipelined sc0sc1 loads, one drain, LDS writes
            U64c tmp[16];
            #pragma unroll
            for (int i = 0; i < 16; i++) {
                int L = i * 256 + tid;          // u64 index; 4096 total
                int r = L >> 7, cc = (L & 127) * 4;
                tmp[i].u = ld_cp64(&hin[(size_t)(rb * 32 + r) * 512 + cc]);
            }
            asm volatile("s_waitcnt vmcnt(0)" ::: "memory");
            __builtin_amdgcn_sched_barrier(0);
            #pragma unroll
            for (int i = 0; i < 16; i++) {
                int L = i * 256 + tid;
                int r = L >> 7, cc = (L & 127) * 4;
                *(us4*)&As[r][cc] = tmp[i].v;
            }
            __syncthreads();

            f32x4 acc[4] = {};
            #pragma unroll
            for (int kk = 0; kk < 16; kk++) {
                short8 a = *(const short8*)&As[hi * 16 + lr][kk * 32 + lg * 8];
                acc[0] = __builtin_amdgcn_mfma_f32_16x16x32_bf16(a, bq[0][kk], acc[0], 0, 0, 0);
                acc[1] = __builtin_amdgcn_mfma_f32_16x16x32_bf16(a, bq[1][kk], acc[1], 0, 0, 0);
                acc[2] = __builtin_amdgcn_mfma_f32_16x16x32_bf16(a, bq[2][kk], acc[2], 0, 0, 0);
                acc[3] = __builtin_amdgcn_mfma_f32_16x16x32_bf16(a, bq[3][kk], acc[3], 0, 0, 0);
            }

            // lane-local epilogue; h + HnewC stores sc0sc1, BEFORE the drain
            #pragma unroll
            for (int i = 0; i < 4; i++) {
                int act = (t < edec[i]);
                float iv = sigm(acc[0][i] + xq[0][i]);
                float fv = sigm(acc[1][i] + xq[1][i]);
                float gv = tanhf(acc[2][i] + xq[2][i]);
                float ov = sigm(acc[3][i] + xq[3][i]);
                float cn = fv * creg[i] + iv * gv;
                float hn_f = ov * tanhf(cn);
                if (act) {
                    creg[i] = cn;
                    hreg[i] = f2bf(hn_f);
                }
                st_cp16(&hout[(size_t)rowg[i] * 512 + col], (unsigned)hreg[i]);
                if (act)
                    st_cp16(&HnewC[(size_t)(offt + rowg[i]) * 512 + col], (unsigned)hreg[i]);
            }

            // drain all sc0sc1 stores, then post this step's completion
            asm volatile("s_waitcnt vmcnt(0)" ::: "memory");
            __syncthreads();
            if (tid == 0) atomicAdd(cnt, 1u);   // after step t: cnt = 16*(t+2)
        }
    } else {
        // ======================= consumer =======================
        u16 (*As)[40] = (u16(*)[40])smem;               // 10240 B
        u16 (*Bs)[40] = (u16(*)[40])(smem + 10240);     // 10240 B
        const int f = wg - NLSTM;
        const int w = tid >> 6, l = tid & 63;
        const int wr = (w >> 1) * 64, wc = (w & 1) * 64;
        const int lr = l & 15, lg = l >> 4;

        int nrC = offs[49];
        int nzero = 6272 - nrC;
        int nzjobs = (nzero + 1) >> 1;
        int nrt = (nrC + 127) >> 7;
        int total = 784 + nzjobs + nrt * 79;

        for (int j = f; j < total; j += NFC) {
            if (j < 784) {
                // ---- X tile: X[tt][:, cbx*128..] = Xemb[tt] @ WihB^T + bsum ----
                int tt = j >> 4, cbx = j & 15;
                f32x4 acc[4][4] = {};
                tile_gemm_plain(Xemb + (size_t)tt * 128 * 512, 512,
                                WihB + (size_t)cbx * 128 * 512, 512,
                                512, tid, As, Bs, acc);
                #pragma unroll
                for (int m = 0; m < 4; m++)
                    #pragma unroll
                    for (int n = 0; n < 4; n++)
                        #pragma unroll
                        for (int i = 0; i < 4; i++) {
                            int row = wr + m * 16 + lg * 4 + i;
                            int colg = cbx * 128 + wc + n * 16 + lr;
                            st_cp32f(&X[(size_t)tt * 262144 + (size_t)row * 2048 + colg],
                                     acc[m][n][i] + bsum[colg]);
                        }
                asm volatile("s_waitcnt vmcnt(0)" ::: "memory");
                __syncthreads();
                if (tid == 0) atomicAdd(&xcnt[tt * 32], 1u);
            } else if (j < 784 + nzjobs) {
                // ---- zero-fill two masked out-rows ----
                int z = (j - 784) * 2;
                #pragma unroll
                for (int rr = 0; rr < 2; rr++) {
                    if (z + rr < nzero) {
                        float* dst = out + (size_t)maskmap[z + rr] * 10000;
                        f32x4 zv = {};
                        for (int i = tid; i < 2500; i += 256) *(f32x4*)&dst[i * 4] = zv;
                    }
                }
            } else {
                // ---- fc tile on compacted rows; PLAIN A loads (L2-cached) ----
                int jf = j - 784 - nzjobs;
                int rt = jf / 79, cn = jf - rt * 79;
                int lastrow = min(rt * 128 + 127, nrC - 1);
                int tmax = rowmap[lastrow] >> 7;
                unsigned tgt = 16u * (unsigned)(tmax + 2);   // init + steps 0..tmax
                if (tid < 4) {
                    const unsigned* cp = slots + tid * 32;
                    while (ld_cp32_wait(cp) < tgt) __builtin_amdgcn_s_sleep(1);
                }
                __syncthreads();

                f32x4 acc[4][4] = {};
                for (int k0 = 0; k0 < 512; k0 += 32) {
                    __syncthreads();
                    #pragma unroll
                    for (int i = 0; i < 2; i++) {
                        int L = tid * 8 + i * 2048;
                        int r = L >> 5, c = L & 31;
                        int gr = rt * 128 + r;
                        short8 a = {};
                        if (gr < nrC) a = *(const short8*)&HnewC[(size_t)gr * 512 + k0 + c];
                        *(short8*)&As[r][c] = a;
                        int gn = cn * 128 + r;
                        short8 b = {};
                        if (gn < NV) b = *(const short8*)&fcWB[(size_t)gn * 512 + k0 + c];
                        *(short8*)&Bs[r][c] = b;
                    }
                    __syncthreads();
                    short8 af[4], bfr[4];
                    #pragma unroll
                    for (int m = 0; m < 4; m++) af[m] = *(const short8*)&As[wr + m * 16 + lr][lg * 8];
                    #pragma unroll
                    for (int n = 0; n < 4; n++) bfr[n] = *(const short8*)&Bs[wc + n * 16 + lr][lg * 8];
                    #pragma unroll
                    for (int m = 0; m < 4; m++)
                        #pragma unroll
                        for (int n = 0; n < 4; n++)
                            acc[m][n] = __builtin_amdgcn_mfma_f32_16x16x32_bf16(af[m], bfr[n], acc[m][n], 0, 0, 0);
                }

                #pragma unroll
                for (int m = 0; m < 4; m++)
                    #pragma unroll
                    for (int n = 0; n < 4; n++)
                        #pragma unroll
                        for (int i = 0; i < 4; i++) {
                            int row = rt * 128 + wr + m * 16 + lg * 4 + i;
                            int colg = cn * 128 + wc + n * 16 + lr;
                            if (row < nrC && colg < NV) {
                                int map = rowmap[row];
                                int b = map & 127, tt = map >> 7;
                                out[(size_t)(b * 49 + tt) * 10000 + colg] =
                                    acc[m][n][i] + fcb[colg];
                            }
                        }
            }
        }
    }
}

extern "C" void kernel_launch(void* const* d_in, const int* in_sizes, int n_in,
                              void* d_out, int out_size, void* d_ws, size_t ws_size,
                              hipStream_t stream) {
    const float* enc      = (const float*)d_in[0];
    const int*   captions = (const int*)d_in[1];
    const int*   caplens  = (const int*)d_in[2];
    const float* embW     = (const float*)d_in[3];
    const float* Wih      = (const float*)d_in[4];
    const float* Whh      = (const float*)d_in[5];
    const float* bih      = (const float*)d_in[6];
    const float* bhh      = (const float*)d_in[7];
    const float* fcW      = (const float*)d_in[8];
    const float* fcb      = (const float*)d_in[9];
    const float* ihW      = (const float*)d_in[10];
    const float* ihb      = (const float*)d_in[11];
    const float* icW      = (const float*)d_in[12];
    const float* icb      = (const float*)d_in[13];
    float* out = (float*)d_out;

    char* ws = (char*)d_ws;
    u16*   WihB = (u16*)(ws + 0);
    u16*   WhhB = (u16*)(ws + 2097152);
    u16*   fcWB = (u16*)(ws + 4194304);
    u16*   WhcB = (u16*)(ws + 14434304);
    u16*   encB = (u16*)(ws + 18628608);
    u16*   Xemb = (u16*)(ws + 19152896);
    float* X    = (float*)(ws + 25575424);
    u16*   HnewC= (u16*)(ws + 76955648);
    u16*   hb0  = (u16*)(ws + 83378176);
    u16*   hb1  = (u16*)(ws + 83509248);
    int*   sidx = (int*)(ws + 83902464);
    int*   decl = (int*)(ws + 83902976);
    int*   capsS= (int*)(ws + 83903488);
    float* bsum = (float*)(ws + 83929088);
    unsigned* slots = (unsigned*)(ws + 83937280);   // 4 h counters @ rb*32
    int*   offs   = (int*)(ws + 83938304);          // 50 ints; offs[49] = nrowsC
    int*   rowmap = (int*)(ws + 83938560);          // 6272 ints
    int*   maskmap= (int*)(ws + 83963648);          // 6272 ints
    unsigned* xcnt = (unsigned*)(ws + 83988736);    // 49 counters @ t*32

    k_sort<<<1, 128, 0, stream>>>(caplens, captions, bih, bhh, sidx, decl, capsS, bsum,
                                  out + 62720000, slots, xcnt, offs, rowmap, maskmap);
    k_cvt<<<9096, 256, 0, stream>>>(Wih, Whh, fcW, ihW, icW, WihB, WhhB, fcWB, WhcB);
    k_gather<<<3392, 256, 0, stream>>>(enc, embW, sidx, capsS, encB, Xemb);
    // fused: h0/c0 (in producers) + X precompute + zero-fill + 49 steps + fc GEMM
    lstm_fc<<<NLSTM + NFC, 256, SMEM_BYTES, stream>>>(
        WhhB, X, hb0, hb1, HnewC, decl, slots, xcnt, offs, rowmap, maskmap,
        fcWB, fcb, encB, WhcB, WihB, Xemb, bsum, ihb, icb, out);
}

// Round 12
// 367.758 us; speedup vs baseline: 1.8098x; 1.1758x over previous
//
#include <hip/hip_runtime.h>
#include <hip/hip_bf16.h>
#include <math.h>

typedef __attribute__((ext_vector_type(8))) short short8;
typedef __attribute__((ext_vector_type(4))) float f32x4;
typedef __attribute__((ext_vector_type(4))) unsigned short us4;
typedef unsigned short u16;
typedef unsigned long long u64;

#define TM 49
#define NV 10000
#define NLSTM 64
#define NFC 192
#define SMEM_BYTES 133120

__device__ __forceinline__ u16 f2bf(float f) {
    union { float f; unsigned u; } v; v.f = f;
    unsigned r = v.u + 0x7fffu + ((v.u >> 16) & 1u);
    return (u16)(r >> 16);
}
__device__ __forceinline__ float fsigm(float x) {
    return 1.0f / (1.0f + __expf(-x));
}
__device__ __forceinline__ float ftanh(float x) {
    float x2 = fminf(fmaxf(x + x, -30.0f), 30.0f);
    float e = __expf(x2);
    return (e - 1.0f) / (e + 1.0f);
}

// coherence-point access helpers (sc0 sc1 = bypass L1+L2, device coherence point)
__device__ __forceinline__ short8 ld_cp128(const u16* p) {
    short8 r;
    asm volatile("global_load_dwordx4 %0, %1, off sc0 sc1" : "=v"(r) : "v"(p));
    return r;   // caller must s_waitcnt before use
}
__device__ __forceinline__ void st_cp16(u16* p, unsigned v) {
    asm volatile("global_store_short %0, %1, off sc0 sc1" :: "v"(p), "v"(v) : "memory");
}
__device__ __forceinline__ void st_cp32f(float* p, float v) {
    asm volatile("global_store_dword %0, %1, off sc0 sc1" :: "v"(p), "v"(v) : "memory");
}
__device__ __forceinline__ unsigned ld_cp32_wait(const unsigned* p) {
    unsigned r;
    asm volatile("global_load_dword %0, %1, off sc0 sc1\n\ts_waitcnt vmcnt(0)"
                 : "=v"(r) : "v"(p) : "memory");
    return r;
}

// ---------------- sort + metadata + compaction tables + small outputs ----------------
__global__ __launch_bounds__(128) void k_sort(
    const int* __restrict__ caplens, const int* __restrict__ captions,
    const float* __restrict__ bih, const float* __restrict__ bhh,
    int* __restrict__ sidx, int* __restrict__ decl, int* __restrict__ capsS,
    float* __restrict__ bsum, float* __restrict__ out_tail,
    unsigned* __restrict__ slots, unsigned* __restrict__ xcnt,
    int* __restrict__ offs, int* __restrict__ rowmap, int* __restrict__ maskmap)
{
    __shared__ int s_cl[128];
    __shared__ int s_si[128];
    __shared__ int s_dl[128];
    __shared__ int s_n[49];
    __shared__ int s_off[50];
    __shared__ int s_moff[128];
    int tid = threadIdx.x;
    for (int k = tid; k < 256; k += 128)    // reset h-group counters
        __hip_atomic_store(&slots[k], 0u, __ATOMIC_RELAXED, __HIP_MEMORY_SCOPE_AGENT);
    for (int k = tid; k < 1568; k += 128)   // reset per-t X counters
        __hip_atomic_store(&xcnt[k], 0u, __ATOMIC_RELAXED, __HIP_MEMORY_SCOPE_AGENT);
    int my = caplens[tid];
    s_cl[tid] = my;
    __syncthreads();
    int r = 0;
    for (int j = 0; j < 128; j++) {
        int cj = s_cl[j];
        if (cj > my || (cj == my && j < tid)) r++;
    }
    s_si[r] = tid;   // stable descending argsort
    __syncthreads();
    int src = s_si[tid];
    sidx[tid] = src;
    int dl = s_cl[src] - 1;
    decl[tid] = dl;
    s_dl[tid] = dl;
    out_tail[6400 + tid] = (float)dl;
    out_tail[6528 + tid] = (float)src;
    for (int t = 0; t < 50; t++) {
        int tok = captions[src * 50 + t];
        capsS[tid * 50 + t] = tok;
        out_tail[tid * 50 + t] = (float)tok;
    }
    for (int k = tid; k < 2048; k += 128) bsum[k] = bih[k] + bhh[k];
    __syncthreads();
    if (tid < 49) {
        int c = 0;
        for (int b = 0; b < 128; b++) c += (s_dl[b] > tid);
        s_n[tid] = c;
    }
    __syncthreads();
    if (tid == 0) {
        int a = 0;
        for (int t = 0; t < 49; t++) { s_off[t] = a; a += s_n[t]; }
        s_off[49] = a;   // total compacted rows
        int m = 0;
        for (int b = 0; b < 128; b++) { s_moff[b] = m; m += 49 - s_dl[b]; }
    }
    __syncthreads();
    if (tid < 50) offs[tid] = s_off[tid];
    for (int t = 0; t < dl; t++) rowmap[s_off[t] + tid] = t * 128 + tid;
    int mo = s_moff[tid];
    for (int t = dl; t < 49; t++) maskmap[mo + (t - dl)] = tid * 49 + t;
}

// ---------------- weight fp32 -> bf16 conversion ----------------
__global__ __launch_bounds__(256) void k_cvt(
    const float* __restrict__ Wih, const float* __restrict__ Whh,
    const float* __restrict__ fcW, const float* __restrict__ ihW,
    const float* __restrict__ icW,
    u16* __restrict__ WihB, u16* __restrict__ WhhB,
    u16* __restrict__ fcWB, u16* __restrict__ WhcB)
{
    int idx = blockIdx.x * 256 + threadIdx.x;  // float4 index, exact grid
    const float* src; u16* dst; int o;
    if (idx < 262144)        { src = Wih; dst = WihB; o = idx; }
    else if (idx < 524288)   { src = Whh; dst = WhhB; o = idx - 262144; }
    else if (idx < 1804288)  { src = fcW; dst = fcWB; o = idx - 524288; }
    else if (idx < 2066432)  { src = ihW; dst = WhcB; o = idx - 1804288; }
    else                     { src = icW; dst = WhcB + 1048576; o = idx - 2066432; }
    f32x4 v = *(const f32x4*)&src[(size_t)o * 4];
    us4 b = { f2bf(v.x), f2bf(v.y), f2bf(v.z), f2bf(v.w) };
    *(us4*)&dst[(size_t)o * 4] = b;
}

// ---------------- gathers: sorted enc -> bf16, embedding -> bf16 ----------------
__global__ __launch_bounds__(256) void k_gather(
    const float* __restrict__ enc, const float* __restrict__ embW,
    const int* __restrict__ sidx, const int* __restrict__ capsS,
    u16* __restrict__ encB, u16* __restrict__ Xemb)
{
    int idx = blockIdx.x * 256 + threadIdx.x;
    if (idx < 65536) {
        int b = idx >> 9, k4 = idx & 511;
        f32x4 v = *(const f32x4*)&enc[(size_t)sidx[b] * 2048 + k4 * 4];
        us4 o = { f2bf(v.x), f2bf(v.y), f2bf(v.z), f2bf(v.w) };
        *(us4*)&encB[(size_t)b * 2048 + k4 * 4] = o;
    } else {
        int j = idx - 65536;              // < 802816
        int row = j >> 7, k4 = j & 127;   // row = t*128 + b
        int t = row >> 7, b = row & 127;
        int tok = capsS[b * 50 + t];
        f32x4 v = *(const f32x4*)&embW[(size_t)tok * 512 + k4 * 4];
        us4 o = { f2bf(v.x), f2bf(v.y), f2bf(v.z), f2bf(v.w) };
        *(us4*)&Xemb[(size_t)row * 512 + k4 * 4] = o;
    }
}

// ---- shared 128x128 tile GEMM body (plain loads, full 128 valid rows both sides) ----
__device__ __forceinline__ void tile_gemm_plain(
    const u16* __restrict__ A, int lda, const u16* __restrict__ B, int ldb,
    int K, int tid, u16 (*As)[40], u16 (*Bs)[40], f32x4 acc[4][4])
{
    const int w = tid >> 6, l = tid & 63;
    const int wr = (w >> 1) * 64, wc = (w & 1) * 64;
    const int lr = l & 15, lg = l >> 4;
    for (int k0 = 0; k0 < K; k0 += 32) {
        __syncthreads();
        #pragma unroll
        for (int i = 0; i < 2; i++) {
            int L = tid * 8 + i * 2048;
            int r = L >> 5, c = L & 31;
            *(short8*)&As[r][c] = *(const short8*)&A[(size_t)r * lda + k0 + c];
            *(short8*)&Bs[r][c] = *(const short8*)&B[(size_t)r * ldb + k0 + c];
        }
        __syncthreads();
        short8 af[4], bfr[4];
        #pragma unroll
        for (int m = 0; m < 4; m++) af[m] = *(const short8*)&As[wr + m * 16 + lr][lg * 8];
        #pragma unroll
        for (int n = 0; n < 4; n++) bfr[n] = *(const short8*)&Bs[wc + n * 16 + lr][lg * 8];
        #pragma unroll
        for (int m = 0; m < 4; m++)
            #pragma unroll
            for (int n = 0; n < 4; n++)
                acc[m][n] = __builtin_amdgcn_mfma_f32_16x16x32_bf16(af[m], bfr[n], acc[m][n], 0, 0, 0);
    }
}

// ---------------- fused persistent kernel ----------------
// blocks 0..63:   LSTM producers (own h0/c0 init; parallel-poll gates; sc0sc1
//                 h-exchange; counter post per step).
// blocks 64..255: consumers. Phase 1: 784 X tiles (post xcnt[t]). Phase 2:
//                 zero-fill masked out rows. Phase 3: fc column-owner — B panel
//                 in LDS once, sweep row-tiles with a barrier-free K-loop
//                 (A fragments direct global->reg), gated on producer counters.
__global__ __launch_bounds__(256, 1) void lstm_fc(
    const u16* __restrict__ Whh, float* __restrict__ X,
    u16* __restrict__ hb0, u16* __restrict__ hb1,
    u16* __restrict__ HnewC,
    const int* __restrict__ decl, unsigned* __restrict__ slots,
    unsigned* __restrict__ xcnt,
    const int* __restrict__ offs, const int* __restrict__ rowmap,
    const int* __restrict__ maskmap,
    const u16* __restrict__ fcWB, const float* __restrict__ fcb,
    const u16* __restrict__ encB, const u16* __restrict__ WhcB,
    const u16* __restrict__ WihB, const u16* __restrict__ Xemb,
    const float* __restrict__ bsum,
    const float* __restrict__ ihb, const float* __restrict__ icb,
    float* __restrict__ out)
{
    extern __shared__ char smem[];
    const int tid = threadIdx.x;
    const int wg = blockIdx.x;

    if (wg < NLSTM) {
        // ======================= recurrence producer =======================
        u16 (*As)[520] = (u16(*)[520])smem;              // 33280 B
        u16 (*Bsi)[520] = (u16(*)[520])(smem + 33280);   // 33280 B (init only)
        const int rb = wg >> 4, cb = wg & 15;
        const int w = tid >> 6, l = tid & 63;
        const int hi = w >> 1, lo = w & 1;
        const int lr = l & 15, lg = l >> 4;
        unsigned* cnt = slots + rb * 32;

        const int col = cb * 32 + lo * 16 + lr;
        int rowg[4];
        #pragma unroll
        for (int i = 0; i < 4; i++) rowg[i] = rb * 32 + hi * 16 + lg * 4 + i;

        // ---- init: h0/c0 for this WG's 32x32 patches (K=2048, 4 chunks) ----
        f32x4 acch = {}, accc = {};
        for (int kq = 0; kq < 4; kq++) {
            __syncthreads();
            #pragma unroll
            for (int i = 0; i < 8; i++) {
                int L = tid * 8 + i * 2048;
                int r = L >> 9, cc = L & 511;
                *(short8*)&As[r][cc] =
                    *(const short8*)&encB[(size_t)(rb * 32 + r) * 2048 + kq * 512 + cc];
                *(short8*)&Bsi[r][cc] =
                    *(const short8*)&WhcB[(size_t)(cb * 32 + r) * 2048 + kq * 512 + cc];
            }
            __syncthreads();
            #pragma unroll
            for (int kk = 0; kk < 16; kk++) {
                short8 a = *(const short8*)&As[hi * 16 + lr][kk * 32 + lg * 8];
                short8 b = *(const short8*)&Bsi[lo * 16 + lr][kk * 32 + lg * 8];
                acch = __builtin_amdgcn_mfma_f32_16x16x32_bf16(a, b, acch, 0, 0, 0);
            }
            __syncthreads();
            #pragma unroll
            for (int i = 0; i < 8; i++) {
                int L = tid * 8 + i * 2048;
                int r = L >> 9, cc = L & 511;
                *(short8*)&Bsi[r][cc] =
                    *(const short8*)&WhcB[(size_t)(512 + cb * 32 + r) * 2048 + kq * 512 + cc];
            }
            __syncthreads();
            #pragma unroll
            for (int kk = 0; kk < 16; kk++) {
                short8 a = *(const short8*)&As[hi * 16 + lr][kk * 32 + lg * 8];
                short8 b = *(const short8*)&Bsi[lo * 16 + lr][kk * 32 + lg * 8];
                accc = __builtin_amdgcn_mfma_f32_16x16x32_bf16(a, b, accc, 0, 0, 0);
            }
        }

        int edec[4];
        f32x4 creg;
        us4 hreg;
        #pragma unroll
        for (int i = 0; i < 4; i++) {
            edec[i] = decl[rowg[i]];
            creg[i] = accc[i] + icb[col];
            hreg[i] = f2bf(acch[i] + ihb[col]);
            st_cp16(&hb0[(size_t)rowg[i] * 512 + col], (unsigned)hreg[i]);
        }
        asm volatile("s_waitcnt vmcnt(0)" ::: "memory");
        __syncthreads();
        if (tid == 0) atomicAdd(cnt, 1u);   // init publish -> cnt reaches 16/group

        // ---- Whh fragments into registers (plain; L2/L3) ----
        short8 bq[4][16];
        #pragma unroll
        for (int q = 0; q < 4; q++) {
            const u16* base = &Whh[(size_t)(q * 512 + cb * 32 + lo * 16 + lr) * 512 + lg * 8];
            #pragma unroll
            for (int kk = 0; kk < 16; kk++)
                bq[q][kk] = *(const short8*)&base[kk * 32];
        }
        #pragma unroll
        for (int q = 0; q < 4; q++)
            #pragma unroll
            for (int kk = 0; kk < 16; kk++)
                asm volatile("" : "+v"(bq[q][kk]));   // pin: no remat of weight loads

        for (int t = 0; t < TM; t++) {
            const u16* hin = (t & 1) ? hb1 : hb0;
            u16* hout = (t & 1) ? hb0 : hb1;

            // combined gate: h(t-1) in-group (lane 0) AND X[t] ready (lane 64), parallel
            {
                unsigned tgt_h = 16u * (unsigned)(t + 1);
                if (tid == 0) {
                    while (ld_cp32_wait(cnt) < tgt_h) __builtin_amdgcn_s_sleep(1);
                } else if (tid == 64) {
                    while (ld_cp32_wait(&xcnt[t * 32]) < 16u) __builtin_amdgcn_s_sleep(1);
                }
                __syncthreads();
            }

            // X[t] gate addends: plain loads (first touch fresh), overlap staging
            float xq[4][4];
            #pragma unroll
            for (int q = 0; q < 4; q++)
                #pragma unroll
                for (int i = 0; i < 4; i++)
                    xq[q][i] = X[(size_t)t * 262144 + (size_t)rowg[i] * 2048 + q * 512 + col];
            int offt = offs[t];

            // stage 32x512 h tile: 8 pipelined sc0sc1 x4 loads, one drain, LDS writes
            short8 tmp[8];
            #pragma unroll
            for (int i = 0; i < 8; i++) {
                int L = i * 256 + tid;          // 16B-chunk index; 2048 total
                int r = L >> 6, cc = (L & 63) * 8;
                tmp[i] = ld_cp128(&hin[(size_t)(rb * 32 + r) * 512 + cc]);
            }
            asm volatile("s_waitcnt vmcnt(0)" ::: "memory");
            __builtin_amdgcn_sched_barrier(0);
            #pragma unroll
            for (int i = 0; i < 8; i++) {
                int L = i * 256 + tid;
                int r = L >> 6, cc = (L & 63) * 8;
                *(short8*)&As[r][cc] = tmp[i];
            }
            __syncthreads();

            f32x4 acc[4] = {};
            #pragma unroll
            for (int kk = 0; kk < 16; kk++) {
                short8 a = *(const short8*)&As[hi * 16 + lr][kk * 32 + lg * 8];
                acc[0] = __builtin_amdgcn_mfma_f32_16x16x32_bf16(a, bq[0][kk], acc[0], 0, 0, 0);
                acc[1] = __builtin_amdgcn_mfma_f32_16x16x32_bf16(a, bq[1][kk], acc[1], 0, 0, 0);
                acc[2] = __builtin_amdgcn_mfma_f32_16x16x32_bf16(a, bq[2][kk], acc[2], 0, 0, 0);
                acc[3] = __builtin_amdgcn_mfma_f32_16x16x32_bf16(a, bq[3][kk], acc[3], 0, 0, 0);
            }

            // lane-local epilogue; h + HnewC stores sc0sc1, BEFORE the drain
            #pragma unroll
            for (int i = 0; i < 4; i++) {
                int act = (t < edec[i]);
                float iv = fsigm(acc[0][i] + xq[0][i]);
                float fv = fsigm(acc[1][i] + xq[1][i]);
                float gv = ftanh(acc[2][i] + xq[2][i]);
                float ov = fsigm(acc[3][i] + xq[3][i]);
                float cn = fv * creg[i] + iv * gv;
                float hn_f = ov * ftanh(cn);
                if (act) {
                    creg[i] = cn;
                    hreg[i] = f2bf(hn_f);
                }
                st_cp16(&hout[(size_t)rowg[i] * 512 + col], (unsigned)hreg[i]);
                if (act)
                    st_cp16(&HnewC[(size_t)(offt + rowg[i]) * 512 + col], (unsigned)hreg[i]);
            }

            // drain all sc0sc1 stores, then post this step's completion
            asm volatile("s_waitcnt vmcnt(0)" ::: "memory");
            __syncthreads();
            if (tid == 0) atomicAdd(cnt, 1u);   // after step t: cnt = 16*(t+2)
        }
    } else {
        // ======================= consumer =======================
        const int f = wg - NLSTM;
        const int w = tid >> 6, l = tid & 63;
        const int wr = (w >> 1) * 64, wc = (w & 1) * 64;
        const int lr = l & 15, lg = l >> 4;

        int nrC = offs[49];
        int nzero = 6272 - nrC;
        int nzjobs = (nzero + 1) >> 1;
        int nrt = (nrC + 127) >> 7;

        // ---- phase 1: X tiles (784 jobs round-robin) ----
        {
            u16 (*As)[40] = (u16(*)[40])smem;
            u16 (*Bs)[40] = (u16(*)[40])(smem + 10240);
            for (int j = f; j < 784; j += NFC) {
                int tt = j >> 4, cbx = j & 15;
                f32x4 acc[4][4] = {};
                tile_gemm_plain(Xemb + (size_t)tt * 128 * 512, 512,
                                WihB + (size_t)cbx * 128 * 512, 512,
                                512, tid, As, Bs, acc);
                #pragma unroll
                for (int m = 0; m < 4; m++)
                    #pragma unroll
                    for (int n = 0; n < 4; n++)
                        #pragma unroll
                        for (int i = 0; i < 4; i++) {
                            int row = wr + m * 16 + lg * 4 + i;
                            int colg = cbx * 128 + wc + n * 16 + lr;
                            st_cp32f(&X[(size_t)tt * 262144 + (size_t)row * 2048 + colg],
                                     acc[m][n][i] + bsum[colg]);
                        }
                asm volatile("s_waitcnt vmcnt(0)" ::: "memory");
                __syncthreads();
                if (tid == 0) atomicAdd(&xcnt[tt * 32], 1u);
            }
        }

        // ---- phase 2: zero-fill masked out rows ----
        for (int j = f; j < nzjobs; j += NFC) {
            int z = j * 2;
            #pragma unroll
            for (int rr = 0; rr < 2; rr++) {
                if (z + rr < nzero) {
                    float* dst = out + (size_t)maskmap[z + rr] * 10000;
                    f32x4 zv = {};
                    for (int i = tid; i < 2500; i += 256) *(f32x4*)&dst[i * 4] = zv;
                }
            }
        }

        // ---- phase 3: fc column-owner; B panel resident in LDS ----
        int c = f % 79;               // owned column tile
        int sub = f / 79;             // 0,1 (2 only for c < 34)
        int gsize = (c < 34) ? 3 : 2;

        u16 (*BT)[520] = (u16(*)[520])smem;   // 128 x 520 u16 = 133120 B
        __syncthreads();   // phase-1 LDS fully retired before overwrite
        #pragma unroll
        for (int i = 0; i < 32; i++) {
            int L = i * 256 + tid;            // short8 index; 8192 = 128 x 64
            int r = L >> 6, cc = (L & 63) * 8;
            int gn = c * 128 + r;
            short8 b = {};
            if (gn < NV) b = *(const short8*)&fcWB[(size_t)gn * 512 + cc];
            *(short8*)&BT[r][cc] = b;
        }
        __syncthreads();

        for (int rt = sub; rt < nrt; rt += gsize) {
            int lastrow = min(rt * 128 + 127, nrC - 1);
            int tmax = rowmap[lastrow] >> 7;
            unsigned tgt = 16u * (unsigned)(tmax + 2);   // init + steps 0..tmax
            if (tid < 4) {
                const unsigned* cp = slots + tid * 32;
                while (ld_cp32_wait(cp) < tgt) __builtin_amdgcn_s_sleep(1);
            }
            __syncthreads();

            // barrier-free K-loop: A fragments direct global->reg, B from LDS
            f32x4 acc[4][4] = {};
            #pragma unroll
            for (int ks = 0; ks < 16; ks++) {
                short8 af[4], bfr[4];
                #pragma unroll
                for (int m = 0; m < 4; m++) {
                    int gr = rt * 128 + wr + m * 16 + lr;
                    short8 a = {};
                    if (gr < nrC)
                        a = *(const short8*)&HnewC[(size_t)gr * 512 + ks * 32 + lg * 8];
                    af[m] = a;
                }
                #pragma unroll
                for (int n = 0; n < 4; n++)
                    bfr[n] = *(const short8*)&BT[wc + n * 16 + lr][ks * 32 + lg * 8];
                #pragma unroll
                for (int m = 0; m < 4; m++)
                    #pragma unroll
                    for (int n = 0; n < 4; n++)
                        acc[m][n] = __builtin_amdgcn_mfma_f32_16x16x32_bf16(af[m], bfr[n], acc[m][n], 0, 0, 0);
            }

            #pragma unroll
            for (int m = 0; m < 4; m++)
                #pragma unroll
                for (int n = 0; n < 4; n++)
                    #pragma unroll
                    for (int i = 0; i < 4; i++) {
                        int row = rt * 128 + wr + m * 16 + lg * 4 + i;
                        int colg = c * 128 + wc + n * 16 + lr;
                        if (row < nrC && colg < NV) {
                            int map = rowmap[row];
                            int b = map & 127, tt = map >> 7;
                            out[(size_t)(b * 49 + tt) * 10000 + colg] =
                                acc[m][n][i] + fcb[colg];
                        }
                    }
        }
    }
}

extern "C" void kernel_launch(void* const* d_in, const int* in_sizes, int n_in,
                              void* d_out, int out_size, void* d_ws, size_t ws_size,
                              hipStream_t stream) {
    const float* enc      = (const float*)d_in[0];
    const int*   captions = (const int*)d_in[1];
    const int*   caplens  = (const int*)d_in[2];
    const float* embW     = (const float*)d_in[3];
    const float* Wih      = (const float*)d_in[4];
    const float* Whh      = (const float*)d_in[5];
    const float* bih      = (const float*)d_in[6];
    const float* bhh      = (const float*)d_in[7];
    const float* fcW      = (const float*)d_in[8];
    const float* fcb      = (const float*)d_in[9];
    const float* ihW      = (const float*)d_in[10];
    const float* ihb      = (const float*)d_in[11];
    const float* icW      = (const float*)d_in[12];
    const float* icb      = (const float*)d_in[13];
    float* out = (float*)d_out;

    char* ws = (char*)d_ws;
    u16*   WihB = (u16*)(ws + 0);
    u16*   WhhB = (u16*)(ws + 2097152);
    u16*   fcWB = (u16*)(ws + 4194304);
    u16*   WhcB = (u16*)(ws + 14434304);
    u16*   encB = (u16*)(ws + 18628608);
    u16*   Xemb = (u16*)(ws + 19152896);
    float* X    = (float*)(ws + 25575424);
    u16*   HnewC= (u16*)(ws + 76955648);
    u16*   hb0  = (u16*)(ws + 83378176);
    u16*   hb1  = (u16*)(ws + 83509248);
    int*   sidx = (int*)(ws + 83902464);
    int*   decl = (int*)(ws + 83902976);
    int*   capsS= (int*)(ws + 83903488);
    float* bsum = (float*)(ws + 83929088);
    unsigned* slots = (unsigned*)(ws + 83937280);   // 4 h counters @ rb*32
    int*   offs   = (int*)(ws + 83938304);          // 50 ints; offs[49] = nrowsC
    int*   rowmap = (int*)(ws + 83938560);          // 6272 ints
    int*   maskmap= (int*)(ws + 83963648);          // 6272 ints
    unsigned* xcnt = (unsigned*)(ws + 83988736);    // 49 counters @ t*32

    k_sort<<<1, 128, 0, stream>>>(caplens, captions, bih, bhh, sidx, decl, capsS, bsum,
                                  out + 62720000, slots, xcnt, offs, rowmap, maskmap);
    k_cvt<<<9096, 256, 0, stream>>>(Wih, Whh, fcW, ihW, icW, WihB, WhhB, fcWB, WhcB);
    k_gather<<<3392, 256, 0, stream>>>(enc, embW, sidx, capsS, encB, Xemb);
    // fused: h0/c0 (in producers) + X precompute + zero-fill + 49 steps + fc GEMM
    lstm_fc<<<NLSTM + NFC, 256, SMEM_BYTES, stream>>>(
        WhhB, X, hb0, hb1, HnewC, decl, slots, xcnt, offs, rowmap, maskmap,
        fcWB, fcb, encB, WhcB, WihB, Xemb, bsum, ihb, icb, out);
}

// Round 13
// 350.195 us; speedup vs baseline: 1.9006x; 1.0502x over previous
//
#include <hip/hip_runtime.h>
#include <hip/hip_bf16.h>
#include <math.h>

typedef __attribute__((ext_vector_type(8))) short short8;
typedef __attribute__((ext_vector_type(4))) float f32x4;
typedef __attribute__((ext_vector_type(4))) unsigned short us4;
typedef unsigned short u16;
typedef unsigned long long u64;

#define TM 49
#define NV 10000
#define NLSTM 64
#define NFC 192
#define SMEM_BYTES 133184

__device__ __forceinline__ u16 f2bf(float f) {
    union { float f; unsigned u; } v; v.f = f;
    unsigned r = v.u + 0x7fffu + ((v.u >> 16) & 1u);
    return (u16)(r >> 16);
}
__device__ __forceinline__ float fsigm(float x) {
    return 1.0f / (1.0f + __expf(-x));
}
__device__ __forceinline__ float ftanh(float x) {
    float x2 = fminf(fmaxf(x + x, -30.0f), 30.0f);
    float e = __expf(x2);
    return (e - 1.0f) / (e + 1.0f);
}

// coherence-point access helpers (sc0 sc1 = bypass L1+L2, device coherence point)
__device__ __forceinline__ short8 ld_cp128(const u16* p) {
    short8 r;
    asm volatile("global_load_dwordx4 %0, %1, off sc0 sc1" : "=v"(r) : "v"(p));
    return r;   // caller must s_waitcnt before use
}
__device__ __forceinline__ void st_cp16(u16* p, unsigned v) {
    asm volatile("global_store_short %0, %1, off sc0 sc1" :: "v"(p), "v"(v) : "memory");
}
__device__ __forceinline__ void st_cp32f(float* p, float v) {
    asm volatile("global_store_dword %0, %1, off sc0 sc1" :: "v"(p), "v"(v) : "memory");
}
__device__ __forceinline__ unsigned ld_cp32_wait(const unsigned* p) {
    unsigned r;
    asm volatile("global_load_dword %0, %1, off sc0 sc1\n\ts_waitcnt vmcnt(0)"
                 : "=v"(r) : "v"(p) : "memory");
    return r;
}

// ---------------- sort + metadata + compaction tables + small outputs ----------------
__global__ __launch_bounds__(128) void k_sort(
    const int* __restrict__ caplens, const int* __restrict__ captions,
    const float* __restrict__ bih, const float* __restrict__ bhh,
    int* __restrict__ sidx, int* __restrict__ decl, int* __restrict__ capsS,
    float* __restrict__ bsum, float* __restrict__ out_tail,
    unsigned* __restrict__ slots, unsigned* __restrict__ xcnt,
    int* __restrict__ offs, int* __restrict__ rowmap, int* __restrict__ maskmap)
{
    __shared__ int s_cl[128];
    __shared__ int s_si[128];
    __shared__ int s_dl[128];
    __shared__ int s_n[49];
    __shared__ int s_off[50];
    __shared__ int s_moff[128];
    int tid = threadIdx.x;
    for (int k = tid; k < 256; k += 128)    // reset h-group counters
        __hip_atomic_store(&slots[k], 0u, __ATOMIC_RELAXED, __HIP_MEMORY_SCOPE_AGENT);
    for (int k = tid; k < 1568; k += 128)   // reset per-t X counters
        __hip_atomic_store(&xcnt[k], 0u, __ATOMIC_RELAXED, __HIP_MEMORY_SCOPE_AGENT);
    int my = caplens[tid];
    s_cl[tid] = my;
    __syncthreads();
    int r = 0;
    for (int j = 0; j < 128; j++) {
        int cj = s_cl[j];
        if (cj > my || (cj == my && j < tid)) r++;
    }
    s_si[r] = tid;   // stable descending argsort
    __syncthreads();
    int src = s_si[tid];
    sidx[tid] = src;
    int dl = s_cl[src] - 1;
    decl[tid] = dl;
    s_dl[tid] = dl;
    out_tail[6400 + tid] = (float)dl;
    out_tail[6528 + tid] = (float)src;
    for (int t = 0; t < 50; t++) {
        int tok = captions[src * 50 + t];
        capsS[tid * 50 + t] = tok;
        out_tail[tid * 50 + t] = (float)tok;
    }
    for (int k = tid; k < 2048; k += 128) bsum[k] = bih[k] + bhh[k];
    __syncthreads();
    if (tid < 49) {
        int c = 0;
        for (int b = 0; b < 128; b++) c += (s_dl[b] > tid);
        s_n[tid] = c;
    }
    __syncthreads();
    if (tid == 0) {
        int a = 0;
        for (int t = 0; t < 49; t++) { s_off[t] = a; a += s_n[t]; }
        s_off[49] = a;   // total compacted rows
        int m = 0;
        for (int b = 0; b < 128; b++) { s_moff[b] = m; m += 49 - s_dl[b]; }
    }
    __syncthreads();
    if (tid < 50) offs[tid] = s_off[tid];
    for (int t = 0; t < dl; t++) rowmap[s_off[t] + tid] = t * 128 + tid;
    int mo = s_moff[tid];
    for (int t = dl; t < 49; t++) maskmap[mo + (t - dl)] = tid * 49 + t;
}

// ---------------- weight fp32 -> bf16 conversion ----------------
__global__ __launch_bounds__(256) void k_cvt(
    const float* __restrict__ Wih, const float* __restrict__ Whh,
    const float* __restrict__ fcW, const float* __restrict__ ihW,
    const float* __restrict__ icW,
    u16* __restrict__ WihB, u16* __restrict__ WhhB,
    u16* __restrict__ fcWB, u16* __restrict__ WhcB)
{
    int idx = blockIdx.x * 256 + threadIdx.x;  // float4 index, exact grid
    const float* src; u16* dst; int o;
    if (idx < 262144)        { src = Wih; dst = WihB; o = idx; }
    else if (idx < 524288)   { src = Whh; dst = WhhB; o = idx - 262144; }
    else if (idx < 1804288)  { src = fcW; dst = fcWB; o = idx - 524288; }
    else if (idx < 2066432)  { src = ihW; dst = WhcB; o = idx - 1804288; }
    else                     { src = icW; dst = WhcB + 1048576; o = idx - 2066432; }
    f32x4 v = *(const f32x4*)&src[(size_t)o * 4];
    us4 b = { f2bf(v.x), f2bf(v.y), f2bf(v.z), f2bf(v.w) };
    *(us4*)&dst[(size_t)o * 4] = b;
}

// ---------------- gathers: sorted enc -> bf16, embedding -> bf16 ----------------
__global__ __launch_bounds__(256) void k_gather(
    const float* __restrict__ enc, const float* __restrict__ embW,
    const int* __restrict__ sidx, const int* __restrict__ capsS,
    u16* __restrict__ encB, u16* __restrict__ Xemb)
{
    int idx = blockIdx.x * 256 + threadIdx.x;
    if (idx < 65536) {
        int b = idx >> 9, k4 = idx & 511;
        f32x4 v = *(const f32x4*)&enc[(size_t)sidx[b] * 2048 + k4 * 4];
        us4 o = { f2bf(v.x), f2bf(v.y), f2bf(v.z), f2bf(v.w) };
        *(us4*)&encB[(size_t)b * 2048 + k4 * 4] = o;
    } else {
        int j = idx - 65536;              // < 802816
        int row = j >> 7, k4 = j & 127;   // row = t*128 + b
        int t = row >> 7, b = row & 127;
        int tok = capsS[b * 50 + t];
        f32x4 v = *(const f32x4*)&embW[(size_t)tok * 512 + k4 * 4];
        us4 o = { f2bf(v.x), f2bf(v.y), f2bf(v.z), f2bf(v.w) };
        *(us4*)&Xemb[(size_t)row * 512 + k4 * 4] = o;
    }
}

// ---- shared 128x128 tile GEMM body (plain loads, full 128 valid rows both sides) ----
__device__ __forceinline__ void tile_gemm_plain(
    const u16* __restrict__ A, int lda, const u16* __restrict__ B, int ldb,
    int K, int tid, u16 (*As)[40], u16 (*Bs)[40], f32x4 acc[4][4])
{
    const int w = tid >> 6, l = tid & 63;
    const int wr = (w >> 1) * 64, wc = (w & 1) * 64;
    const int lr = l & 15, lg = l >> 4;
    for (int k0 = 0; k0 < K; k0 += 32) {
        __syncthreads();
        #pragma unroll
        for (int i = 0; i < 2; i++) {
            int L = tid * 8 + i * 2048;
            int r = L >> 5, c = L & 31;
            *(short8*)&As[r][c] = *(const short8*)&A[(size_t)r * lda + k0 + c];
            *(short8*)&Bs[r][c] = *(const short8*)&B[(size_t)r * ldb + k0 + c];
        }
        __syncthreads();
        short8 af[4], bfr[4];
        #pragma unroll
        for (int m = 0; m < 4; m++) af[m] = *(const short8*)&As[wr + m * 16 + lr][lg * 8];
        #pragma unroll
        for (int n = 0; n < 4; n++) bfr[n] = *(const short8*)&Bs[wc + n * 16 + lr][lg * 8];
        #pragma unroll
        for (int m = 0; m < 4; m++)
            #pragma unroll
            for (int n = 0; n < 4; n++)
                acc[m][n] = __builtin_amdgcn_mfma_f32_16x16x32_bf16(af[m], bfr[n], acc[m][n], 0, 0, 0);
    }
}

// ---------------- fused persistent kernel ----------------
// blocks 0..63:   LSTM producers (own h0/c0 init; parallel-poll gates; sc0sc1
//                 h-exchange; counter post per step).
// blocks 64..255: consumers. Phase 1: 784 X tiles (post xcnt[t]). Phase 2: fc
//                 column-owner — B panel in LDS once, sweep row-tiles with a
//                 barrier-free K-loop; gate-waits consumed by opportunistic
//                 zero-fill of masked out rows (non-temporal stores).
__global__ __launch_bounds__(256, 1) void lstm_fc(
    const u16* __restrict__ Whh, float* __restrict__ X,
    u16* __restrict__ hb0, u16* __restrict__ hb1,
    u16* __restrict__ HnewC,
    const int* __restrict__ decl, unsigned* __restrict__ slots,
    unsigned* __restrict__ xcnt,
    const int* __restrict__ offs, const int* __restrict__ rowmap,
    const int* __restrict__ maskmap,
    const u16* __restrict__ fcWB, const float* __restrict__ fcb,
    const u16* __restrict__ encB, const u16* __restrict__ WhcB,
    const u16* __restrict__ WihB, const u16* __restrict__ Xemb,
    const float* __restrict__ bsum,
    const float* __restrict__ ihb, const float* __restrict__ icb,
    float* __restrict__ out)
{
    extern __shared__ char smem[];
    const int tid = threadIdx.x;
    const int wg = blockIdx.x;

    if (wg < NLSTM) {
        // ======================= recurrence producer =======================
        u16 (*As)[520] = (u16(*)[520])smem;              // 33280 B
        u16 (*Bsi)[520] = (u16(*)[520])(smem + 33280);   // 33280 B (init only)
        const int rb = wg >> 4, cb = wg & 15;
        const int w = tid >> 6, l = tid & 63;
        const int hi = w >> 1, lo = w & 1;
        const int lr = l & 15, lg = l >> 4;
        unsigned* cnt = slots + rb * 32;

        const int col = cb * 32 + lo * 16 + lr;
        int rowg[4];
        #pragma unroll
        for (int i = 0; i < 4; i++) rowg[i] = rb * 32 + hi * 16 + lg * 4 + i;

        // ---- init: h0/c0 for this WG's 32x32 patches (K=2048, 4 chunks) ----
        f32x4 acch = {}, accc = {};
        for (int kq = 0; kq < 4; kq++) {
            __syncthreads();
            #pragma unroll
            for (int i = 0; i < 8; i++) {
                int L = tid * 8 + i * 2048;
                int r = L >> 9, cc = L & 511;
                *(short8*)&As[r][cc] =
                    *(const short8*)&encB[(size_t)(rb * 32 + r) * 2048 + kq * 512 + cc];
                *(short8*)&Bsi[r][cc] =
                    *(const short8*)&WhcB[(size_t)(cb * 32 + r) * 2048 + kq * 512 + cc];
            }
            __syncthreads();
            #pragma unroll
            for (int kk = 0; kk < 16; kk++) {
                short8 a = *(const short8*)&As[hi * 16 + lr][kk * 32 + lg * 8];
                short8 b = *(const short8*)&Bsi[lo * 16 + lr][kk * 32 + lg * 8];
                acch = __builtin_amdgcn_mfma_f32_16x16x32_bf16(a, b, acch, 0, 0, 0);
            }
            __syncthreads();
            #pragma unroll
            for (int i = 0; i < 8; i++) {
                int L = tid * 8 + i * 2048;
                int r = L >> 9, cc = L & 511;
                *(short8*)&Bsi[r][cc] =
                    *(const short8*)&WhcB[(size_t)(512 + cb * 32 + r) * 2048 + kq * 512 + cc];
            }
            __syncthreads();
            #pragma unroll
            for (int kk = 0; kk < 16; kk++) {
                short8 a = *(const short8*)&As[hi * 16 + lr][kk * 32 + lg * 8];
                short8 b = *(const short8*)&Bsi[lo * 16 + lr][kk * 32 + lg * 8];
                accc = __builtin_amdgcn_mfma_f32_16x16x32_bf16(a, b, accc, 0, 0, 0);
            }
        }

        int edec[4];
        f32x4 creg;
        us4 hreg;
        #pragma unroll
        for (int i = 0; i < 4; i++) {
            edec[i] = decl[rowg[i]];
            creg[i] = accc[i] + icb[col];
            hreg[i] = f2bf(acch[i] + ihb[col]);
            st_cp16(&hb0[(size_t)rowg[i] * 512 + col], (unsigned)hreg[i]);
        }
        asm volatile("s_waitcnt vmcnt(0)" ::: "memory");
        __syncthreads();
        if (tid == 0) atomicAdd(cnt, 1u);   // init publish -> cnt reaches 16/group

        // ---- Whh fragments into registers (plain; L2/L3) ----
        short8 bq[4][16];
        #pragma unroll
        for (int q = 0; q < 4; q++) {
            const u16* base = &Whh[(size_t)(q * 512 + cb * 32 + lo * 16 + lr) * 512 + lg * 8];
            #pragma unroll
            for (int kk = 0; kk < 16; kk++)
                bq[q][kk] = *(const short8*)&base[kk * 32];
        }
        #pragma unroll
        for (int q = 0; q < 4; q++)
            #pragma unroll
            for (int kk = 0; kk < 16; kk++)
                asm volatile("" : "+v"(bq[q][kk]));   // pin: no remat of weight loads

        for (int t = 0; t < TM; t++) {
            const u16* hin = (t & 1) ? hb1 : hb0;
            u16* hout = (t & 1) ? hb0 : hb1;

            // combined gate: h(t-1) in-group (lane 0) AND X[t] ready (lane 64), parallel
            {
                unsigned tgt_h = 16u * (unsigned)(t + 1);
                if (tid == 0) {
                    while (ld_cp32_wait(cnt) < tgt_h) __builtin_amdgcn_s_sleep(1);
                } else if (tid == 64) {
                    while (ld_cp32_wait(&xcnt[t * 32]) < 16u) __builtin_amdgcn_s_sleep(1);
                }
                __syncthreads();
            }

            // X[t] gate addends: plain loads (first touch fresh), overlap staging
            float xq[4][4];
            #pragma unroll
            for (int q = 0; q < 4; q++)
                #pragma unroll
                for (int i = 0; i < 4; i++)
                    xq[q][i] = X[(size_t)t * 262144 + (size_t)rowg[i] * 2048 + q * 512 + col];
            int offt = offs[t];

            // stage 32x512 h tile: 8 pipelined sc0sc1 x4 loads, one drain, LDS writes
            short8 tmp[8];
            #pragma unroll
            for (int i = 0; i < 8; i++) {
                int L = i * 256 + tid;          // 16B-chunk index; 2048 total
                int r = L >> 6, cc = (L & 63) * 8;
                tmp[i] = ld_cp128(&hin[(size_t)(rb * 32 + r) * 512 + cc]);
            }
            asm volatile("s_waitcnt vmcnt(0)" ::: "memory");
            __builtin_amdgcn_sched_barrier(0);
            #pragma unroll
            for (int i = 0; i < 8; i++) {
                int L = i * 256 + tid;
                int r = L >> 6, cc = (L & 63) * 8;
                *(short8*)&As[r][cc] = tmp[i];
            }
            __syncthreads();

            f32x4 acc[4] = {};
            #pragma unroll
            for (int kk = 0; kk < 16; kk++) {
                short8 a = *(const short8*)&As[hi * 16 + lr][kk * 32 + lg * 8];
                acc[0] = __builtin_amdgcn_mfma_f32_16x16x32_bf16(a, bq[0][kk], acc[0], 0, 0, 0);
                acc[1] = __builtin_amdgcn_mfma_f32_16x16x32_bf16(a, bq[1][kk], acc[1], 0, 0, 0);
                acc[2] = __builtin_amdgcn_mfma_f32_16x16x32_bf16(a, bq[2][kk], acc[2], 0, 0, 0);
                acc[3] = __builtin_amdgcn_mfma_f32_16x16x32_bf16(a, bq[3][kk], acc[3], 0, 0, 0);
            }

            // lane-local epilogue; h + HnewC stores sc0sc1, BEFORE the drain
            #pragma unroll
            for (int i = 0; i < 4; i++) {
                int act = (t < edec[i]);
                float iv = fsigm(acc[0][i] + xq[0][i]);
                float fv = fsigm(acc[1][i] + xq[1][i]);
                float gv = ftanh(acc[2][i] + xq[2][i]);
                float ov = fsigm(acc[3][i] + xq[3][i]);
                float cn = fv * creg[i] + iv * gv;
                float hn_f = ov * ftanh(cn);
                if (act) {
                    creg[i] = cn;
                    hreg[i] = f2bf(hn_f);
                }
                st_cp16(&hout[(size_t)rowg[i] * 512 + col], (unsigned)hreg[i]);
                if (act)
                    st_cp16(&HnewC[(size_t)(offt + rowg[i]) * 512 + col], (unsigned)hreg[i]);
            }

            // drain all sc0sc1 stores, then post this step's completion
            asm volatile("s_waitcnt vmcnt(0)" ::: "memory");
            __syncthreads();
            if (tid == 0) atomicAdd(cnt, 1u);   // after step t: cnt = 16*(t+2)
        }
    } else {
        // ======================= consumer =======================
        const int f = wg - NLSTM;
        const int w = tid >> 6, l = tid & 63;
        const int wr = (w >> 1) * 64, wc = (w & 1) * 64;
        const int lr = l & 15, lg = l >> 4;

        int nrC = offs[49];
        int nzero = 6272 - nrC;
        int nrt = (nrC + 127) >> 7;

        // ---- phase 1: X tiles (784 jobs round-robin) ----
        {
            u16 (*As)[40] = (u16(*)[40])smem;
            u16 (*Bs)[40] = (u16(*)[40])(smem + 10240);
            for (int j = f; j < 784; j += NFC) {
                int tt = j >> 4, cbx = j & 15;
                f32x4 acc[4][4] = {};
                tile_gemm_plain(Xemb + (size_t)tt * 128 * 512, 512,
                                WihB + (size_t)cbx * 128 * 512, 512,
                                512, tid, As, Bs, acc);
                #pragma unroll
                for (int m = 0; m < 4; m++)
                    #pragma unroll
                    for (int n = 0; n < 4; n++)
                        #pragma unroll
                        for (int i = 0; i < 4; i++) {
                            int row = wr + m * 16 + lg * 4 + i;
                            int colg = cbx * 128 + wc + n * 16 + lr;
                            st_cp32f(&X[(size_t)tt * 262144 + (size_t)row * 2048 + colg],
                                     acc[m][n][i] + bsum[colg]);
                        }
                asm volatile("s_waitcnt vmcnt(0)" ::: "memory");
                __syncthreads();
                if (tid == 0) atomicAdd(&xcnt[tt * 32], 1u);
            }
        }

        // ---- phase 2: fc column-owner; B panel resident in LDS; gate-waits
        //      consumed by opportunistic zero-fill of masked out rows ----
        int c = f % 79;               // owned column tile
        int sub = f / 79;             // 0,1 (2 only for c < 34)
        int gsize = (c < 34) ? 3 : 2;

        u16 (*BT)[520] = (u16(*)[520])smem;                 // 133120 B
        unsigned* s_cnt = (unsigned*)(smem + 133120);       // 4 u32
        __syncthreads();   // phase-1 LDS fully retired before overwrite
        #pragma unroll
        for (int i = 0; i < 32; i++) {
            int L = i * 256 + tid;            // short8 index; 8192 = 128 x 64
            int r = L >> 6, cc = (L & 63) * 8;
            int gn = c * 128 + r;
            short8 b = {};
            if (gn < NV) b = *(const short8*)&fcWB[(size_t)gn * 512 + cc];
            *(short8*)&BT[r][cc] = b;
        }
        __syncthreads();

        int znext = f;   // this consumer's masked-row zero jobs: f, f+NFC, ...
        f32x4 zv = {};

        for (int rt = sub; rt < nrt; rt += gsize) {
            int lastrow = min(rt * 128 + 127, nrC - 1);
            int tmax = rowmap[lastrow] >> 7;
            unsigned tgt = 16u * (unsigned)(tmax + 2);   // init + steps 0..tmax

            // gate with productive waiting
            while (true) {
                if (tid < 4) s_cnt[tid] = ld_cp32_wait(slots + tid * 32);
                __syncthreads();
                bool rdy = (s_cnt[0] >= tgt) && (s_cnt[1] >= tgt) &&
                           (s_cnt[2] >= tgt) && (s_cnt[3] >= tgt);
                __syncthreads();
                if (rdy) break;
                if (znext < nzero) {
                    float* dst = out + (size_t)maskmap[znext] * 10000;
                    for (int i = tid; i < 2500; i += 256)
                        __builtin_nontemporal_store(zv, (f32x4*)&dst[i * 4]);
                    znext += NFC;
                } else {
                    __builtin_amdgcn_s_sleep(16);
                }
            }

            // barrier-free K-loop: A fragments direct global->reg, B from LDS
            f32x4 acc[4][4] = {};
            #pragma unroll
            for (int ks = 0; ks < 16; ks++) {
                short8 af[4], bfr[4];
                #pragma unroll
                for (int m = 0; m < 4; m++) {
                    int gr = rt * 128 + wr + m * 16 + lr;
                    short8 a = {};
                    if (gr < nrC)
                        a = *(const short8*)&HnewC[(size_t)gr * 512 + ks * 32 + lg * 8];
                    af[m] = a;
                }
                #pragma unroll
                for (int n = 0; n < 4; n++)
                    bfr[n] = *(const short8*)&BT[wc + n * 16 + lr][ks * 32 + lg * 8];
                #pragma unroll
                for (int m = 0; m < 4; m++)
                    #pragma unroll
                    for (int n = 0; n < 4; n++)
                        acc[m][n] = __builtin_amdgcn_mfma_f32_16x16x32_bf16(af[m], bfr[n], acc[m][n], 0, 0, 0);
            }

            #pragma unroll
            for (int m = 0; m < 4; m++)
                #pragma unroll
                for (int n = 0; n < 4; n++)
                    #pragma unroll
                    for (int i = 0; i < 4; i++) {
                        int row = rt * 128 + wr + m * 16 + lg * 4 + i;
                        int colg = c * 128 + wc + n * 16 + lr;
                        if (row < nrC && colg < NV) {
                            int map = rowmap[row];
                            int b = map & 127, tt = map >> 7;
                            __builtin_nontemporal_store(
                                acc[m][n][i] + fcb[colg],
                                &out[(size_t)(b * 49 + tt) * 10000 + colg]);
                        }
                    }
        }

        // leftover zero jobs
        while (znext < nzero) {
            float* dst = out + (size_t)maskmap[znext] * 10000;
            for (int i = tid; i < 2500; i += 256)
                __builtin_nontemporal_store(zv, (f32x4*)&dst[i * 4]);
            znext += NFC;
        }
    }
}

extern "C" void kernel_launch(void* const* d_in, const int* in_sizes, int n_in,
                              void* d_out, int out_size, void* d_ws, size_t ws_size,
                              hipStream_t stream) {
    const float* enc      = (const float*)d_in[0];
    const int*   captions = (const int*)d_in[1];
    const int*   caplens  = (const int*)d_in[2];
    const float* embW     = (const float*)d_in[3];
    const float* Wih      = (const float*)d_in[4];
    const float* Whh      = (const float*)d_in[5];
    const float* bih      = (const float*)d_in[6];
    const float* bhh      = (const float*)d_in[7];
    const float* fcW      = (const float*)d_in[8];
    const float* fcb      = (const float*)d_in[9];
    const float* ihW      = (const float*)d_in[10];
    const float* ihb      = (const float*)d_in[11];
    const float* icW      = (const float*)d_in[12];
    const float* icb      = (const float*)d_in[13];
    float* out = (float*)d_out;

    char* ws = (char*)d_ws;
    u16*   WihB = (u16*)(ws + 0);
    u16*   WhhB = (u16*)(ws + 2097152);
    u16*   fcWB = (u16*)(ws + 4194304);
    u16*   WhcB = (u16*)(ws + 14434304);
    u16*   encB = (u16*)(ws + 18628608);
    u16*   Xemb = (u16*)(ws + 19152896);
    float* X    = (float*)(ws + 25575424);
    u16*   HnewC= (u16*)(ws + 76955648);
    u16*   hb0  = (u16*)(ws + 83378176);
    u16*   hb1  = (u16*)(ws + 83509248);
    int*   sidx = (int*)(ws + 83902464);
    int*   decl = (int*)(ws + 83902976);
    int*   capsS= (int*)(ws + 83903488);
    float* bsum = (float*)(ws + 83929088);
    unsigned* slots = (unsigned*)(ws + 83937280);   // 4 h counters @ rb*32
    int*   offs   = (int*)(ws + 83938304);          // 50 ints; offs[49] = nrowsC
    int*   rowmap = (int*)(ws + 83938560);          // 6272 ints
    int*   maskmap= (int*)(ws + 83963648);          // 6272 ints
    unsigned* xcnt = (unsigned*)(ws + 83988736);    // 49 counters @ t*32

    k_sort<<<1, 128, 0, stream>>>(caplens, captions, bih, bhh, sidx, decl, capsS, bsum,
                                  out + 62720000, slots, xcnt, offs, rowmap, maskmap);
    k_cvt<<<9096, 256, 0, stream>>>(Wih, Whh, fcW, ihW, icW, WihB, WhhB, fcWB, WhcB);
    k_gather<<<3392, 256, 0, stream>>>(enc, embW, sidx, capsS, encB, Xemb);
    // fused: h0/c0 (in producers) + X precompute + zero-fill + 49 steps + fc GEMM
    lstm_fc<<<NLSTM + NFC, 256, SMEM_BYTES, stream>>>(
        WhhB, X, hb0, hb1, HnewC, decl, slots, xcnt, offs, rowmap, maskmap,
        fcWB, fcb, encB, WhcB, WihB, Xemb, bsum, ihb, icb, out);
}

// Round 14
// 332.090 us; speedup vs baseline: 2.0042x; 1.0545x over previous
//
#include <hip/hip_runtime.h>
#include <hip/hip_bf16.h>
#include <math.h>

typedef __attribute__((ext_vector_type(8))) short short8;
typedef __attribute__((ext_vector_type(4))) float f32x4;
typedef __attribute__((ext_vector_type(4))) unsigned short us4;
typedef unsigned short u16;
typedef unsigned long long u64;

#define TM 49
#define NV 10000
#define NLSTM 64
#define NFC 192
#define SMEM_BYTES 133184

__device__ __forceinline__ u16 f2bf(float f) {
    union { float f; unsigned u; } v; v.f = f;
    unsigned r = v.u + 0x7fffu + ((v.u >> 16) & 1u);
    return (u16)(r >> 16);
}
__device__ __forceinline__ float fsigm(float x) {
    return 1.0f / (1.0f + __expf(-x));
}
__device__ __forceinline__ float ftanh(float x) {
    float x2 = fminf(fmaxf(x + x, -30.0f), 30.0f);
    float e = __expf(x2);
    return (e - 1.0f) / (e + 1.0f);
}

// coherence-point access helpers (sc0 sc1 = bypass L1+L2, device coherence point)
__device__ __forceinline__ short8 ld_cp128(const u16* p) {
    short8 r;
    asm volatile("global_load_dwordx4 %0, %1, off sc0 sc1" : "=v"(r) : "v"(p));
    return r;   // caller must s_waitcnt before use
}
__device__ __forceinline__ void st_cp16(u16* p, unsigned v) {
    asm volatile("global_store_short %0, %1, off sc0 sc1" :: "v"(p), "v"(v) : "memory");
}
__device__ __forceinline__ void st_cp32f(float* p, float v) {
    asm volatile("global_store_dword %0, %1, off sc0 sc1" :: "v"(p), "v"(v) : "memory");
}
__device__ __forceinline__ void st_cp32u(unsigned* p, unsigned v) {
    asm volatile("global_store_dword %0, %1, off sc0 sc1" :: "v"(p), "v"(v) : "memory");
}
__device__ __forceinline__ unsigned ld_cp32_wait(const unsigned* p) {
    unsigned r;
    asm volatile("global_load_dword %0, %1, off sc0 sc1\n\ts_waitcnt vmcnt(0)"
                 : "=v"(r) : "v"(p) : "memory");
    return r;
}

// ---------------- sort + metadata + compaction tables + small outputs ----------------
__global__ __launch_bounds__(128) void k_sort(
    const int* __restrict__ caplens, const int* __restrict__ captions,
    const float* __restrict__ bih, const float* __restrict__ bhh,
    int* __restrict__ sidx, int* __restrict__ decl, int* __restrict__ capsS,
    float* __restrict__ bsum, float* __restrict__ out_tail,
    unsigned* __restrict__ flags, unsigned* __restrict__ xcnt,
    int* __restrict__ offs, int* __restrict__ rowmap, int* __restrict__ maskmap)
{
    __shared__ int s_cl[128];
    __shared__ int s_si[128];
    __shared__ int s_dl[128];
    __shared__ int s_n[49];
    __shared__ int s_off[50];
    __shared__ int s_moff[128];
    int tid = threadIdx.x;
    for (int k = tid; k < 2048; k += 128)   // reset 64 per-WG flag lines
        __hip_atomic_store(&flags[k], 0u, __ATOMIC_RELAXED, __HIP_MEMORY_SCOPE_AGENT);
    for (int k = tid; k < 1568; k += 128)   // reset per-t X counters
        __hip_atomic_store(&xcnt[k], 0u, __ATOMIC_RELAXED, __HIP_MEMORY_SCOPE_AGENT);
    int my = caplens[tid];
    s_cl[tid] = my;
    __syncthreads();
    int r = 0;
    for (int j = 0; j < 128; j++) {
        int cj = s_cl[j];
        if (cj > my || (cj == my && j < tid)) r++;
    }
    s_si[r] = tid;   // stable descending argsort
    __syncthreads();
    int src = s_si[tid];
    sidx[tid] = src;
    int dl = s_cl[src] - 1;
    decl[tid] = dl;
    s_dl[tid] = dl;
    out_tail[6400 + tid] = (float)dl;
    out_tail[6528 + tid] = (float)src;
    for (int t = 0; t < 50; t++) {
        int tok = captions[src * 50 + t];
        capsS[tid * 50 + t] = tok;
        out_tail[tid * 50 + t] = (float)tok;
    }
    for (int k = tid; k < 2048; k += 128) bsum[k] = bih[k] + bhh[k];
    __syncthreads();
    if (tid < 49) {
        int c = 0;
        for (int b = 0; b < 128; b++) c += (s_dl[b] > tid);
        s_n[tid] = c;
    }
    __syncthreads();
    if (tid == 0) {
        int a = 0;
        for (int t = 0; t < 49; t++) { s_off[t] = a; a += s_n[t]; }
        s_off[49] = a;   // total compacted rows
        int m = 0;
        for (int b = 0; b < 128; b++) { s_moff[b] = m; m += 49 - s_dl[b]; }
    }
    __syncthreads();
    if (tid < 50) offs[tid] = s_off[tid];
    for (int t = 0; t < dl; t++) rowmap[s_off[t] + tid] = t * 128 + tid;
    int mo = s_moff[tid];
    for (int t = dl; t < 49; t++) maskmap[mo + (t - dl)] = tid * 49 + t;
}

// ---------------- weight fp32 -> bf16 conversion ----------------
__global__ __launch_bounds__(256) void k_cvt(
    const float* __restrict__ Wih, const float* __restrict__ Whh,
    const float* __restrict__ fcW, const float* __restrict__ ihW,
    const float* __restrict__ icW,
    u16* __restrict__ WihB, u16* __restrict__ WhhB,
    u16* __restrict__ fcWB, u16* __restrict__ WhcB)
{
    int idx = blockIdx.x * 256 + threadIdx.x;  // float4 index, exact grid
    const float* src; u16* dst; int o;
    if (idx < 262144)        { src = Wih; dst = WihB; o = idx; }
    else if (idx < 524288)   { src = Whh; dst = WhhB; o = idx - 262144; }
    else if (idx < 1804288)  { src = fcW; dst = fcWB; o = idx - 524288; }
    else if (idx < 2066432)  { src = ihW; dst = WhcB; o = idx - 1804288; }
    else                     { src = icW; dst = WhcB + 1048576; o = idx - 2066432; }
    f32x4 v = *(const f32x4*)&src[(size_t)o * 4];
    us4 b = { f2bf(v.x), f2bf(v.y), f2bf(v.z), f2bf(v.w) };
    *(us4*)&dst[(size_t)o * 4] = b;
}

// ---------------- gathers: sorted enc -> bf16, embedding -> bf16 ----------------
__global__ __launch_bounds__(256) void k_gather(
    const float* __restrict__ enc, const float* __restrict__ embW,
    const int* __restrict__ sidx, const int* __restrict__ capsS,
    u16* __restrict__ encB, u16* __restrict__ Xemb)
{
    int idx = blockIdx.x * 256 + threadIdx.x;
    if (idx < 65536) {
        int b = idx >> 9, k4 = idx & 511;
        f32x4 v = *(const f32x4*)&enc[(size_t)sidx[b] * 2048 + k4 * 4];
        us4 o = { f2bf(v.x), f2bf(v.y), f2bf(v.z), f2bf(v.w) };
        *(us4*)&encB[(size_t)b * 2048 + k4 * 4] = o;
    } else {
        int j = idx - 65536;              // < 802816
        int row = j >> 7, k4 = j & 127;   // row = t*128 + b
        int t = row >> 7, b = row & 127;
        int tok = capsS[b * 50 + t];
        f32x4 v = *(const f32x4*)&embW[(size_t)tok * 512 + k4 * 4];
        us4 o = { f2bf(v.x), f2bf(v.y), f2bf(v.z), f2bf(v.w) };
        *(us4*)&Xemb[(size_t)row * 512 + k4 * 4] = o;
    }
}

// ---- shared 128x128 tile GEMM body (plain loads, full 128 valid rows both sides) ----
__device__ __forceinline__ void tile_gemm_plain(
    const u16* __restrict__ A, int lda, const u16* __restrict__ B, int ldb,
    int K, int tid, u16 (*As)[40], u16 (*Bs)[40], f32x4 acc[4][4])
{
    const int w = tid >> 6, l = tid & 63;
    const int wr = (w >> 1) * 64, wc = (w & 1) * 64;
    const int lr = l & 15, lg = l >> 4;
    for (int k0 = 0; k0 < K; k0 += 32) {
        __syncthreads();
        #pragma unroll
        for (int i = 0; i < 2; i++) {
            int L = tid * 8 + i * 2048;
            int r = L >> 5, c = L & 31;
            *(short8*)&As[r][c] = *(const short8*)&A[(size_t)r * lda + k0 + c];
            *(short8*)&Bs[r][c] = *(const short8*)&B[(size_t)r * ldb + k0 + c];
        }
        __syncthreads();
        short8 af[4], bfr[4];
        #pragma unroll
        for (int m = 0; m < 4; m++) af[m] = *(const short8*)&As[wr + m * 16 + lr][lg * 8];
        #pragma unroll
        for (int n = 0; n < 4; n++) bfr[n] = *(const short8*)&Bs[wc + n * 16 + lr][lg * 8];
        #pragma unroll
        for (int m = 0; m < 4; m++)
            #pragma unroll
            for (int n = 0; n < 4; n++)
                acc[m][n] = __builtin_amdgcn_mfma_f32_16x16x32_bf16(af[m], bfr[n], acc[m][n], 0, 0, 0);
    }
}

// ---------------- fused persistent kernel ----------------
// blocks 0..63:   LSTM producers. Per-WG FLAG (no RMW): init posts 1, step t posts
//                 t+2 (after draining only the h stores; HnewC stores deferred past
//                 the post — their visibility is covered by the NEXT step's drain),
//                 final post TM+2 after loop. Gate: 16 parallel flag lanes + lane 16
//                 polling xcnt[t], single-RTT iterations, no sleep.
// blocks 64..255: consumers. Phase 1: 784 X tiles (post xcnt[t]). Phase 2: fc
//                 column-owner; gate = 64-lane parallel flag read >= tmax+3;
//                 gate-waits consumed by zero-fill (non-temporal stores).
__global__ __launch_bounds__(256, 1) void lstm_fc(
    const u16* __restrict__ Whh, float* __restrict__ X,
    u16* __restrict__ hb0, u16* __restrict__ hb1,
    u16* __restrict__ HnewC,
    const int* __restrict__ decl, unsigned* __restrict__ flags,
    unsigned* __restrict__ xcnt,
    const int* __restrict__ offs, const int* __restrict__ rowmap,
    const int* __restrict__ maskmap,
    const u16* __restrict__ fcWB, const float* __restrict__ fcb,
    const u16* __restrict__ encB, const u16* __restrict__ WhcB,
    const u16* __restrict__ WihB, const u16* __restrict__ Xemb,
    const float* __restrict__ bsum,
    const float* __restrict__ ihb, const float* __restrict__ icb,
    float* __restrict__ out)
{
    extern __shared__ char smem[];
    const int tid = threadIdx.x;
    const int wg = blockIdx.x;

    if (wg < NLSTM) {
        // ======================= recurrence producer =======================
        u16 (*As)[520] = (u16(*)[520])smem;              // 33280 B
        u16 (*Bsi)[520] = (u16(*)[520])(smem + 33280);   // 33280 B (init only)
        const int rb = wg >> 4, cb = wg & 15;
        const int w = tid >> 6, l = tid & 63;
        const int hi = w >> 1, lo = w & 1;
        const int lr = l & 15, lg = l >> 4;
        unsigned* myflag = &flags[(rb * 16 + cb) * 32];

        const int col = cb * 32 + lo * 16 + lr;
        int rowg[4];
        #pragma unroll
        for (int i = 0; i < 4; i++) rowg[i] = rb * 32 + hi * 16 + lg * 4 + i;

        // ---- init: h0/c0 for this WG's 32x32 patches (K=2048, 4 chunks) ----
        f32x4 acch = {}, accc = {};
        for (int kq = 0; kq < 4; kq++) {
            __syncthreads();
            #pragma unroll
            for (int i = 0; i < 8; i++) {
                int L = tid * 8 + i * 2048;
                int r = L >> 9, cc = L & 511;
                *(short8*)&As[r][cc] =
                    *(const short8*)&encB[(size_t)(rb * 32 + r) * 2048 + kq * 512 + cc];
                *(short8*)&Bsi[r][cc] =
                    *(const short8*)&WhcB[(size_t)(cb * 32 + r) * 2048 + kq * 512 + cc];
            }
            __syncthreads();
            #pragma unroll
            for (int kk = 0; kk < 16; kk++) {
                short8 a = *(const short8*)&As[hi * 16 + lr][kk * 32 + lg * 8];
                short8 b = *(const short8*)&Bsi[lo * 16 + lr][kk * 32 + lg * 8];
                acch = __builtin_amdgcn_mfma_f32_16x16x32_bf16(a, b, acch, 0, 0, 0);
            }
            __syncthreads();
            #pragma unroll
            for (int i = 0; i < 8; i++) {
                int L = tid * 8 + i * 2048;
                int r = L >> 9, cc = L & 511;
                *(short8*)&Bsi[r][cc] =
                    *(const short8*)&WhcB[(size_t)(512 + cb * 32 + r) * 2048 + kq * 512 + cc];
            }
            __syncthreads();
            #pragma unroll
            for (int kk = 0; kk < 16; kk++) {
                short8 a = *(const short8*)&As[hi * 16 + lr][kk * 32 + lg * 8];
                short8 b = *(const short8*)&Bsi[lo * 16 + lr][kk * 32 + lg * 8];
                accc = __builtin_amdgcn_mfma_f32_16x16x32_bf16(a, b, accc, 0, 0, 0);
            }
        }

        int edec[4];
        f32x4 creg;
        us4 hreg;
        #pragma unroll
        for (int i = 0; i < 4; i++) {
            edec[i] = decl[rowg[i]];
            creg[i] = accc[i] + icb[col];
            hreg[i] = f2bf(acch[i] + ihb[col]);
            st_cp16(&hb0[(size_t)rowg[i] * 512 + col], (unsigned)hreg[i]);
        }
        asm volatile("s_waitcnt vmcnt(0)" ::: "memory");
        __syncthreads();
        if (tid == 0) st_cp32u(myflag, 1u);   // init published

        // ---- Whh fragments into registers (plain; L2/L3) ----
        short8 bq[4][16];
        #pragma unroll
        for (int q = 0; q < 4; q++) {
            const u16* base = &Whh[(size_t)(q * 512 + cb * 32 + lo * 16 + lr) * 512 + lg * 8];
            #pragma unroll
            for (int kk = 0; kk < 16; kk++)
                bq[q][kk] = *(const short8*)&base[kk * 32];
        }
        #pragma unroll
        for (int q = 0; q < 4; q++)
            #pragma unroll
            for (int kk = 0; kk < 16; kk++)
                asm volatile("" : "+v"(bq[q][kk]));   // pin: no remat of weight loads

        for (int t = 0; t < TM; t++) {
            const u16* hin = (t & 1) ? hb1 : hb0;
            u16* hout = (t & 1) ? hb0 : hb1;

            // gate: 16 parallel flag lanes (h(t-1) within group) + lane 16 (X[t])
            if (tid < 64) {
                unsigned tgt_h = (unsigned)(t + 1);
                while (true) {
                    bool ok = true;
                    if (tid < 16)
                        ok = (ld_cp32_wait(&flags[(rb * 16 + tid) * 32]) >= tgt_h);
                    else if (tid == 16)
                        ok = (ld_cp32_wait(&xcnt[t * 32]) >= 16u);
                    if (__all(ok)) break;
                }
            }
            __syncthreads();

            // X[t] gate addends: plain loads (first touch fresh), overlap staging
            float xq[4][4];
            #pragma unroll
            for (int q = 0; q < 4; q++)
                #pragma unroll
                for (int i = 0; i < 4; i++)
                    xq[q][i] = X[(size_t)t * 262144 + (size_t)rowg[i] * 2048 + q * 512 + col];
            int offt = offs[t];

            // stage 32x512 h tile: 8 pipelined sc0sc1 x4 loads, one drain, LDS writes
            short8 tmp[8];
            #pragma unroll
            for (int i = 0; i < 8; i++) {
                int L = i * 256 + tid;          // 16B-chunk index; 2048 total
                int r = L >> 6, cc = (L & 63) * 8;
                tmp[i] = ld_cp128(&hin[(size_t)(rb * 32 + r) * 512 + cc]);
            }
            asm volatile("s_waitcnt vmcnt(0)" ::: "memory");
            __builtin_amdgcn_sched_barrier(0);
            #pragma unroll
            for (int i = 0; i < 8; i++) {
                int L = i * 256 + tid;
                int r = L >> 6, cc = (L & 63) * 8;
                *(short8*)&As[r][cc] = tmp[i];
            }
            __syncthreads();

            f32x4 acc[4] = {};
            #pragma unroll
            for (int kk = 0; kk < 16; kk++) {
                short8 a = *(const short8*)&As[hi * 16 + lr][kk * 32 + lg * 8];
                acc[0] = __builtin_amdgcn_mfma_f32_16x16x32_bf16(a, bq[0][kk], acc[0], 0, 0, 0);
                acc[1] = __builtin_amdgcn_mfma_f32_16x16x32_bf16(a, bq[1][kk], acc[1], 0, 0, 0);
                acc[2] = __builtin_amdgcn_mfma_f32_16x16x32_bf16(a, bq[2][kk], acc[2], 0, 0, 0);
                acc[3] = __builtin_amdgcn_mfma_f32_16x16x32_bf16(a, bq[3][kk], acc[3], 0, 0, 0);
            }

            // lane-local epilogue; h stores sc0sc1 BEFORE the drain
            #pragma unroll
            for (int i = 0; i < 4; i++) {
                int act = (t < edec[i]);
                float iv = fsigm(acc[0][i] + xq[0][i]);
                float fv = fsigm(acc[1][i] + xq[1][i]);
                float gv = ftanh(acc[2][i] + xq[2][i]);
                float ov = fsigm(acc[3][i] + xq[3][i]);
                float cn = fv * creg[i] + iv * gv;
                float hn_f = ov * ftanh(cn);
                if (act) {
                    creg[i] = cn;
                    hreg[i] = f2bf(hn_f);
                }
                st_cp16(&hout[(size_t)rowg[i] * 512 + col], (unsigned)hreg[i]);
            }

            // drain h stores only, post flag, THEN issue HnewC stores (deferred;
            // covered by next step's drain / final drain)
            asm volatile("s_waitcnt vmcnt(0)" ::: "memory");
            __syncthreads();
            if (tid == 0) st_cp32u(myflag, (unsigned)(t + 2));
            #pragma unroll
            for (int i = 0; i < 4; i++)
                if (t < edec[i])
                    st_cp16(&HnewC[(size_t)(offt + rowg[i]) * 512 + col], (unsigned)hreg[i]);
        }

        // final: drain deferred HnewC stores, publish terminal flag
        asm volatile("s_waitcnt vmcnt(0)" ::: "memory");
        __syncthreads();
        if (tid == 0) st_cp32u(myflag, (unsigned)(TM + 2));
    } else {
        // ======================= consumer =======================
        const int f = wg - NLSTM;
        const int w = tid >> 6, l = tid & 63;
        const int wr = (w >> 1) * 64, wc = (w & 1) * 64;
        const int lr = l & 15, lg = l >> 4;

        int nrC = offs[49];
        int nzero = 6272 - nrC;
        int nrt = (nrC + 127) >> 7;

        // ---- phase 1: X tiles (784 jobs round-robin) ----
        {
            u16 (*As)[40] = (u16(*)[40])smem;
            u16 (*Bs)[40] = (u16(*)[40])(smem + 10240);
            for (int j = f; j < 784; j += NFC) {
                int tt = j >> 4, cbx = j & 15;
                f32x4 acc[4][4] = {};
                tile_gemm_plain(Xemb + (size_t)tt * 128 * 512, 512,
                                WihB + (size_t)cbx * 128 * 512, 512,
                                512, tid, As, Bs, acc);
                #pragma unroll
                for (int m = 0; m < 4; m++)
                    #pragma unroll
                    for (int n = 0; n < 4; n++)
                        #pragma unroll
                        for (int i = 0; i < 4; i++) {
                            int row = wr + m * 16 + lg * 4 + i;
                            int colg = cbx * 128 + wc + n * 16 + lr;
                            st_cp32f(&X[(size_t)tt * 262144 + (size_t)row * 2048 + colg],
                                     acc[m][n][i] + bsum[colg]);
                        }
                asm volatile("s_waitcnt vmcnt(0)" ::: "memory");
                __syncthreads();
                if (tid == 0) atomicAdd(&xcnt[tt * 32], 1u);
            }
        }

        // ---- phase 2: fc column-owner; B panel resident in LDS; gate-waits
        //      consumed by opportunistic zero-fill of masked out rows ----
        int c = f % 79;               // owned column tile
        int sub = f / 79;             // 0,1 (2 only for c < 34)
        int gsize = (c < 34) ? 3 : 2;

        u16 (*BT)[520] = (u16(*)[520])smem;                 // 133120 B
        unsigned* s_rdy = (unsigned*)(smem + 133120);       // 1 u32
        __syncthreads();   // phase-1 LDS fully retired before overwrite
        #pragma unroll
        for (int i = 0; i < 32; i++) {
            int L = i * 256 + tid;            // short8 index; 8192 = 128 x 64
            int r = L >> 6, cc = (L & 63) * 8;
            int gn = c * 128 + r;
            short8 b = {};
            if (gn < NV) b = *(const short8*)&fcWB[(size_t)gn * 512 + cc];
            *(short8*)&BT[r][cc] = b;
        }
        __syncthreads();

        int znext = f;   // this consumer's masked-row zero jobs: f, f+NFC, ...
        f32x4 zv = {};

        for (int rt = sub; rt < nrt; rt += gsize) {
            int lastrow = min(rt * 128 + 127, nrC - 1);
            int tmax = rowmap[lastrow] >> 7;
            unsigned tgt = (unsigned)(tmax + 3);   // deferred-HnewC visibility

            // gate with productive waiting: 64-lane parallel flag read
            while (true) {
                bool ok = (tid < 64) ? (ld_cp32_wait(&flags[tid * 32]) >= tgt) : true;
                int allv = __all(ok);
                if (tid == 0) *s_rdy = (unsigned)allv;
                __syncthreads();
                bool rdy = (*s_rdy != 0);
                __syncthreads();
                if (rdy) break;
                if (znext < nzero) {
                    float* dst = out + (size_t)maskmap[znext] * 10000;
                    for (int i = tid; i < 2500; i += 256)
                        __builtin_nontemporal_store(zv, (f32x4*)&dst[i * 4]);
                    znext += NFC;
                } else {
                    __builtin_amdgcn_s_sleep(32);
                }
            }

            // barrier-free K-loop: A fragments direct global->reg, B from LDS
            f32x4 acc[4][4] = {};
            #pragma unroll
            for (int ks = 0; ks < 16; ks++) {
                short8 af[4], bfr[4];
                #pragma unroll
                for (int m = 0; m < 4; m++) {
                    int gr = rt * 128 + wr + m * 16 + lr;
                    short8 a = {};
                    if (gr < nrC)
                        a = *(const short8*)&HnewC[(size_t)gr * 512 + ks * 32 + lg * 8];
                    af[m] = a;
                }
                #pragma unroll
                for (int n = 0; n < 4; n++)
                    bfr[n] = *(const short8*)&BT[wc + n * 16 + lr][ks * 32 + lg * 8];
                #pragma unroll
                for (int m = 0; m < 4; m++)
                    #pragma unroll
                    for (int n = 0; n < 4; n++)
                        acc[m][n] = __builtin_amdgcn_mfma_f32_16x16x32_bf16(af[m], bfr[n], acc[m][n], 0, 0, 0);
            }

            #pragma unroll
            for (int m = 0; m < 4; m++)
                #pragma unroll
                for (int n = 0; n < 4; n++)
                    #pragma unroll
                    for (int i = 0; i < 4; i++) {
                        int row = rt * 128 + wr + m * 16 + lg * 4 + i;
                        int colg = c * 128 + wc + n * 16 + lr;
                        if (row < nrC && colg < NV) {
                            int map = rowmap[row];
                            int b = map & 127, tt = map >> 7;
                            __builtin_nontemporal_store(
                                acc[m][n][i] + fcb[colg],
                                &out[(size_t)(b * 49 + tt) * 10000 + colg]);
                        }
                    }
        }

        // leftover zero jobs
        while (znext < nzero) {
            float* dst = out + (size_t)maskmap[znext] * 10000;
            for (int i = tid; i < 2500; i += 256)
                __builtin_nontemporal_store(zv, (f32x4*)&dst[i * 4]);
            znext += NFC;
        }
    }
}

extern "C" void kernel_launch(void* const* d_in, const int* in_sizes, int n_in,
                              void* d_out, int out_size, void* d_ws, size_t ws_size,
                              hipStream_t stream) {
    const float* enc      = (const float*)d_in[0];
    const int*   captions = (const int*)d_in[1];
    const int*   caplens  = (const int*)d_in[2];
    const float* embW     = (const float*)d_in[3];
    const float* Wih      = (const float*)d_in[4];
    const float* Whh      = (const float*)d_in[5];
    const float* bih      = (const float*)d_in[6];
    const float* bhh      = (const float*)d_in[7];
    const float* fcW      = (const float*)d_in[8];
    const float* fcb      = (const float*)d_in[9];
    const float* ihW      = (const float*)d_in[10];
    const float* ihb      = (const float*)d_in[11];
    const float* icW      = (const float*)d_in[12];
    const float* icb      = (const float*)d_in[13];
    float* out = (float*)d_out;

    char* ws = (char*)d_ws;
    u16*   WihB = (u16*)(ws + 0);
    u16*   WhhB = (u16*)(ws + 2097152);
    u16*   fcWB = (u16*)(ws + 4194304);
    u16*   WhcB = (u16*)(ws + 14434304);
    u16*   encB = (u16*)(ws + 18628608);
    u16*   Xemb = (u16*)(ws + 19152896);
    float* X    = (float*)(ws + 25575424);
    u16*   HnewC= (u16*)(ws + 76955648);
    u16*   hb0  = (u16*)(ws + 83378176);
    u16*   hb1  = (u16*)(ws + 83509248);
    unsigned* flags = (unsigned*)(ws + 83640320);   // 64 flag lines x 128B (old cf region)
    int*   sidx = (int*)(ws + 83902464);
    int*   decl = (int*)(ws + 83902976);
    int*   capsS= (int*)(ws + 83903488);
    float* bsum = (float*)(ws + 83929088);
    int*   offs   = (int*)(ws + 83938304);          // 50 ints; offs[49] = nrowsC
    int*   rowmap = (int*)(ws + 83938560);          // 6272 ints
    int*   maskmap= (int*)(ws + 83963648);          // 6272 ints
    unsigned* xcnt = (unsigned*)(ws + 83988736);    // 49 counters @ t*32

    k_sort<<<1, 128, 0, stream>>>(caplens, captions, bih, bhh, sidx, decl, capsS, bsum,
                                  out + 62720000, flags, xcnt, offs, rowmap, maskmap);
    k_cvt<<<9096, 256, 0, stream>>>(Wih, Whh, fcW, ihW, icW, WihB, WhhB, fcWB, WhcB);
    k_gather<<<3392, 256, 0, stream>>>(enc, embW, sidx, capsS, encB, Xemb);
    // fused: h0/c0 (in producers) + X precompute + zero-fill + 49 steps + fc GEMM
    lstm_fc<<<NLSTM + NFC, 256, SMEM_BYTES, stream>>>(
        WhhB, X, hb0, hb1, HnewC, decl, flags, xcnt, offs, rowmap, maskmap,
        fcWB, fcb, encB, WhcB, WihB, Xemb, bsum, ihb, icb, out);
}